// Round 17
// baseline (203.160 us; speedup 1.0000x reference)
//
#include <hip/hip_runtime.h>
#include <hip/hip_bf16.h>

#define Bn 2
#define Tn 2048
#define Cn 1024
#define Hn 16
#define HSn 64
#define Mn (Bn*Tn)          // 4096
#define LN_EPS 1e-5f

typedef unsigned short u16;
typedef __attribute__((ext_vector_type(8))) short bf16x8;   // 8 bf16 = 4 VGPRs
typedef __attribute__((ext_vector_type(4))) float f32x4;

#define MFMA16(a,b,c) __builtin_amdgcn_mfma_f32_16x16x32_bf16(a, b, c, 0, 0, 0)
#define GLL16(g,l) __builtin_amdgcn_global_load_lds( \
    (const __attribute__((address_space(1))) void*)(g), \
    (__attribute__((address_space(3))) void*)(l), 16, 0, 0)

__device__ __forceinline__ u16 f2b(float f) {               // f32 -> bf16 RNE
    unsigned int u = __float_as_uint(f);
    unsigned int r = (u + 0x7FFFu + ((u >> 16) & 1u)) >> 16;
    return (u16)r;
}
__device__ __forceinline__ float b2f(unsigned u) {          // bf16 -> f32
    return __uint_as_float(u << 16);
}
__device__ __forceinline__ unsigned cvtpk(float lo, float hi) { // [hi|lo] bf16x2
    unsigned r;
    asm("v_cvt_pk_bf16_f32 %0, %1, %2" : "=v"(r) : "v"(lo), "v"(hi));
    return r;
}

// ---------------------------------------------------------------------------
// Shared 64x64 transpose-convert tile body (f32 in -> bf16 out^T).
// ---------------------------------------------------------------------------
__device__ __forceinline__ void trans_tile(
    const float* __restrict__ in, u16* __restrict__ out,
    int R, int C, int r0, int c0c, float (*t)[68], int tid)
{
#pragma unroll
    for (int it = 0; it < 4; it++) {
        int r = it * 16 + (tid >> 4);
        *(float4*)&t[r][(tid & 15) * 4] =
            *(const float4*)(in + (size_t)(r0 + r) * C + c0c + (tid & 15) * 4);
    }
    __syncthreads();
    int c = tid >> 2, seg = tid & 3;
    union { u16 u[8]; uint4 q; } pk;
#pragma unroll
    for (int hq = 0; hq < 2; hq++) {
#pragma unroll
        for (int j = 0; j < 8; j++) pk.u[j] = f2b(t[seg * 16 + hq * 8 + j][c]);
        *(uint4*)(out + (size_t)(c0c + c) * R + r0 + seg * 16 + hq * 8) = pk.q;
    }
}

// ---------------------------------------------------------------------------
// Fused weight repack: all four weight transposes in ONE launch (3072 blocks).
// ---------------------------------------------------------------------------
__global__ __launch_bounds__(256) void repack_all(
    const float* __restrict__ Wq, const float* __restrict__ Wk,
    const float* __restrict__ Wv, u16* __restrict__ WtQKV,
    const float* __restrict__ projw, u16* __restrict__ WtP,
    const float* __restrict__ fc1w, u16* __restrict__ Wt1,
    const float* __restrict__ fc2w, u16* __restrict__ Wt2)
{
    __shared__ float t[64][68];
    const int bid = (int)blockIdx.x, tid = threadIdx.x;
    if (bid < 768) {
        int z = bid >> 8, rem = bid & 255, h = rem >> 4, c0 = (rem & 15) * 64;
        const float* in = (z == 0 ? Wq : z == 1 ? Wk : Wv) + (size_t)h * 65536;
        u16* outb = WtQKV + (size_t)(z * 1024 + h * 64) * 1024;
        trans_tile(in, outb, 1024, 64, c0, 0, t, tid);
    } else if (bid < 1024) {
        int idx = bid - 768, bx = idx & 15, by = idx >> 4;
        trans_tile(projw, WtP, 1024, 1024, by * 64, bx * 64, t, tid);
    } else if (bid < 2048) {
        int idx = bid - 1024, bx = idx & 63, by = idx >> 6;
        trans_tile(fc1w, Wt1, 1024, 4096, by * 64, bx * 64, t, tid);
    } else {
        int idx = bid - 2048, bx = idx & 15, by = idx >> 4;
        trans_tile(fc2w, Wt2, 4096, 1024, by * 64, bx * 64, t, tid);
    }
}

// ---------------------------------------------------------------------------
// LayerNorm f32 in -> bf16 out. One wave per row.
// ---------------------------------------------------------------------------
__global__ __launch_bounds__(256) void ln_bf16(
    const float* __restrict__ x, const float* __restrict__ w,
    const float* __restrict__ bvec, u16* __restrict__ out)
{
    int row  = blockIdx.x * 4 + (threadIdx.x >> 6);
    int lane = threadIdx.x & 63;
    const float* xr = x + (size_t)row * Cn;
    float4 v[4];
    float s = 0.f, sq = 0.f;
#pragma unroll
    for (int i = 0; i < 4; i++) {
        v[i] = *(const float4*)(xr + lane * 4 + i * 256);
        s  += v[i].x + v[i].y + v[i].z + v[i].w;
        sq += v[i].x * v[i].x + v[i].y * v[i].y + v[i].z * v[i].z + v[i].w * v[i].w;
    }
#pragma unroll
    for (int off = 1; off < 64; off <<= 1) {
        s  += __shfl_xor(s, off);
        sq += __shfl_xor(sq, off);
    }
    float mu   = s * (1.f / Cn);
    float var  = sq * (1.f / Cn) - mu * mu;
    float rstd = rsqrtf(var + LN_EPS);
    u16* orow = out + (size_t)row * Cn;
#pragma unroll
    for (int i = 0; i < 4; i++) {
        float4 w4 = *(const float4*)(w    + lane * 4 + i * 256);
        float4 b4 = *(const float4*)(bvec + lane * 4 + i * 256);
        union { u16 u[4]; uint2 q; } pk;
        pk.u[0] = f2b((v[i].x - mu) * rstd * w4.x + b4.x);
        pk.u[1] = f2b((v[i].y - mu) * rstd * w4.y + b4.y);
        pk.u[2] = f2b((v[i].z - mu) * rstd * w4.z + b4.z);
        pk.u[3] = f2b((v[i].w - mu) * rstd * w4.w + b4.w);
        *(uint2*)(orow + lane * 4 + i * 256) = pk.q;
    }
}

// ---------------------------------------------------------------------------
// LayerNorm bf16 in -> bf16 out. One wave per row (16 elems/lane, contiguous).
// ---------------------------------------------------------------------------
__global__ __launch_bounds__(256) void ln_bf16_b(
    const u16* __restrict__ x, const float* __restrict__ w,
    const float* __restrict__ bvec, u16* __restrict__ out)
{
    int row  = blockIdx.x * 4 + (threadIdx.x >> 6);
    int lane = threadIdx.x & 63;
    const u16* xr = x + (size_t)row * Cn + lane * 16;
    float v[16];
    float s = 0.f, sq = 0.f;
#pragma unroll
    for (int i = 0; i < 2; i++) {
        uint4 q = *(const uint4*)(xr + i * 8);
        float* vv = v + i * 8;
        vv[0] = b2f(q.x & 0xffffu); vv[1] = b2f(q.x >> 16);
        vv[2] = b2f(q.y & 0xffffu); vv[3] = b2f(q.y >> 16);
        vv[4] = b2f(q.z & 0xffffu); vv[5] = b2f(q.z >> 16);
        vv[6] = b2f(q.w & 0xffffu); vv[7] = b2f(q.w >> 16);
    }
#pragma unroll
    for (int j = 0; j < 16; j++) { s += v[j]; sq += v[j] * v[j]; }
#pragma unroll
    for (int off = 1; off < 64; off <<= 1) {
        s  += __shfl_xor(s, off);
        sq += __shfl_xor(sq, off);
    }
    float mu   = s * (1.f / Cn);
    float var  = sq * (1.f / Cn) - mu * mu;
    float rstd = rsqrtf(var + LN_EPS);
    u16* orow = out + (size_t)row * Cn + lane * 16;
#pragma unroll
    for (int i = 0; i < 2; i++) {
        union { u16 u[8]; uint4 q; } pk;
#pragma unroll
        for (int j = 0; j < 8; j++) {
            int col = lane * 16 + i * 8 + j;
            pk.u[j] = f2b((v[i * 8 + j] - mu) * rstd * w[col] + bvec[col]);
        }
        *(uint4*)(orow + i * 8) = pk.q;
    }
}

// ---------------------------------------------------------------------------
// FC1 GEMM, 2-blocks/CU, CONFLICT-FIXED layout: tile 128(M) x 256(N), BK=32,
// 8 waves (2M x 4N), LDS 48 KB. Two logical 64B rows packed per 128B LDS row
// (packrow = row>>1, 8 chunks, chunk = ((row&1)*4 + g) ^ (packrow&7)) —
// geometrically identical to the measured-zero BK=64 read pattern.
// Counted-vmcnt 2-barrier loop as round 16.
// ---------------------------------------------------------------------------
__global__ __launch_bounds__(512, 4) void gemm_fc1(
    const u16* __restrict__ A, const u16* __restrict__ Bt,
    const float* __restrict__ bias, u16* __restrict__ Cout)
{
    __shared__ u16 lds[24576];   // A[2][4096] | B[2][8192]  (48 KB)
    const int tid = threadIdx.x, l = tid & 63, w = tid >> 6;
    const int wm = w >> 2, wn = w & 3;
    const int g = l >> 4, c16 = l & 15;
    const int K = 1024, N = 4096;

    const int bid = (int)blockIdx.x;
    const int sbid = (bid & 7) * 64 + (bid >> 3);   // 512 blocks, bijective
    const int m0 = (sbid >> 4) * 128, n0 = (sbid & 15) * 256;

    // A staging: 512 granules (1/thread). granule tid -> packrow tid>>3,
    // chunk8 tid&7; inverse-swizzle to logical (row, kc):
    const int apr = tid >> 3, auc = (tid & 7) ^ (apr & 7);
    const int arow = 2 * apr + (auc >> 2), akc = auc & 3;
    const u16* a0 = A + (size_t)(m0 + arow) * K + akc * 8;
    // B staging: 1024 granules (2/thread)
    const int bG0 = tid, bG1 = tid + 512;
    const int bp0 = bG0 >> 3, bu0 = (bG0 & 7) ^ (bp0 & 7);
    const int bp1 = bG1 >> 3, bu1 = (bG1 & 7) ^ (bp1 & 7);
    const u16* b0 = Bt + (size_t)(n0 + 2 * bp0 + (bu0 >> 2)) * K + (bu0 & 3) * 8;
    const u16* b1 = Bt + (size_t)(n0 + 2 * bp1 + (bu1 >> 2)) * K + (bu1 & 3) * 8;

#define STG_F1(dd, kt) do {                                                   \
        GLL16(a0 + (size_t)(kt) * 32, &lds[(dd) * 4096 + tid * 8]);           \
        GLL16(b0 + (size_t)(kt) * 32, &lds[8192 + (dd) * 8192 + bG0 * 8]);    \
        GLL16(b1 + (size_t)(kt) * 32, &lds[8192 + (dd) * 8192 + bG1 * 8]);    \
    } while (0)
    // reads: logical row R, chunk8 = ((R&1)*4+g) ^ ((R>>1)&7)
#define LDA_F1(dd, mi) (*(const bf16x8*)&lds[(dd) * 4096 +                    \
        ((wm * 64 + (mi) * 16 + c16) >> 1) * 64 +                              \
        (((((wm * 64 + (mi) * 16 + c16) & 1) << 2) + g)                        \
         ^ (((wm * 64 + (mi) * 16 + c16) >> 1) & 7)) * 8])
#define LDB_F1(dd, nj) (*(const bf16x8*)&lds[8192 + (dd) * 8192 +             \
        ((wn * 64 + (nj) * 16 + c16) >> 1) * 64 +                              \
        (((((wn * 64 + (nj) * 16 + c16) & 1) << 2) + g)                        \
         ^ (((wn * 64 + (nj) * 16 + c16) >> 1) & 7)) * 8])

    f32x4 acc[4][4];
#pragma unroll
    for (int i = 0; i < 4; i++)
#pragma unroll
        for (int j = 0; j < 4; j++) acc[i][j] = (f32x4){0.f, 0.f, 0.f, 0.f};

    const int nk = 32;
    STG_F1(0, 0);
    asm volatile("s_waitcnt vmcnt(0)" ::: "memory");
    __builtin_amdgcn_sched_barrier(0);
    __builtin_amdgcn_s_barrier();

    for (int m = 0; m < nk; m++) {
        const int d = m & 1, dn = d ^ 1;
        if (m + 1 < nk) STG_F1(dn, m + 1);
        if (m > 0) {
            if (m + 1 < nk) asm volatile("s_waitcnt vmcnt(3)" ::: "memory");
            else            asm volatile("s_waitcnt vmcnt(0)" ::: "memory");
            __builtin_amdgcn_sched_barrier(0);
            __builtin_amdgcn_s_barrier();
        }
        bf16x8 aF[4], bF[4];
#pragma unroll
        for (int mi = 0; mi < 4; mi++) aF[mi] = LDA_F1(d, mi);
#pragma unroll
        for (int nj = 0; nj < 4; nj++) bF[nj] = LDB_F1(d, nj);
        __builtin_amdgcn_s_setprio(1);
#pragma unroll
        for (int mi = 0; mi < 4; mi++)
#pragma unroll
            for (int nj = 0; nj < 4; nj++)
                acc[mi][nj] = MFMA16(aF[mi], bF[nj], acc[mi][nj]);
        __builtin_amdgcn_s_setprio(0);
        __builtin_amdgcn_s_barrier();
    }
#undef STG_F1
#undef LDA_F1
#undef LDB_F1

#pragma unroll
    for (int mi = 0; mi < 4; mi++)
#pragma unroll
        for (int nj = 0; nj < 4; nj++) {
            const int coln = n0 + wn * 64 + nj * 16 + c16;
            float bv = bias[coln];
#pragma unroll
            for (int reg = 0; reg < 4; reg++) {
                int rowm = m0 + wm * 64 + mi * 16 + 4 * g + reg;
                float v = fmaxf(acc[mi][nj][reg] + bv, 0.f);
                Cout[(size_t)rowm * N + coln] = f2b(v);
            }
        }
}

// ---------------------------------------------------------------------------
// QKV 8-phase GEMM, tile 256(M) x 192(N), BK=64: grid 16x16 = 256 blocks.
// ---------------------------------------------------------------------------
__global__ __launch_bounds__(512, 1) void gemm_qkv(
    const u16* __restrict__ A, const u16* __restrict__ Bt,
    u16* __restrict__ Cout)
{
    __shared__ u16 lds[57344];                 // A 2x32KB | B 2x24KB = 112 KiB
    const int tid = threadIdx.x, l = tid & 63, w = tid >> 6;
    const int wm = w >> 1, wn = w & 1;         // 4M x 2N waves
    const int g = l >> 4, c16 = l & 15;
    const int K = 1024, N = 3072;

    const int bid = (int)blockIdx.x;
    const int sbid = (bid & 7) * 32 + (bid >> 3);      // grid 256, bijective
    const int m0 = (sbid >> 4) * 256, n0 = (sbid & 15) * 192;

    const int sr = tid >> 3;
    const int ss = ((tid & 7) ^ (sr & 7)) << 3;
    const u16* Asrc = A  + (size_t)(m0 + sr) * K + ss;
    const u16* Bsrc = Bt + (size_t)(n0 + sr) * K + ss;
    const int dst0 = tid * 8;

#define ST_A(d_, h_, kt_) do {                                               \
        GLL16(Asrc + (size_t)((h_) * 128) * K + (size_t)(kt_) * 64,          \
              &lds[(d_) * 16384 + (h_) * 8192 + dst0]);                      \
        GLL16(Asrc + (size_t)((h_) * 128 + 64) * K + (size_t)(kt_) * 64,     \
              &lds[(d_) * 16384 + (h_) * 8192 + 4096 + dst0]);               \
    } while (0)
#define ST_B1(d_, seg_, kt_)                                                 \
        GLL16(Bsrc + (size_t)((seg_) * 64) * K + (size_t)(kt_) * 64,         \
              &lds[32768 + (d_) * 12288 + (seg_) * 4096 + dst0])
#define LDA(d_, mi_, s_) (*(const bf16x8*)&lds[(d_) * 16384 +                \
        (wm * 64 + (mi_) * 16 + c16) * 64 +                                   \
        ((((s_) * 4 + g) ^ ((wm * 64 + (mi_) * 16 + c16) & 7)) << 3)])
#define LDB(d_, nj_, s_) (*(const bf16x8*)&lds[32768 + (d_) * 12288 +        \
        (wn * 96 + (nj_) * 16 + c16) * 64 +                                   \
        ((((s_) * 4 + g) ^ ((wn * 96 + (nj_) * 16 + c16) & 7)) << 3)])
#define PH_HEAD() do {                                                       \
        __builtin_amdgcn_s_barrier();                                        \
        asm volatile("s_waitcnt lgkmcnt(0)" ::: "memory");                   \
        __builtin_amdgcn_sched_barrier(0);                                   \
        __builtin_amdgcn_s_setprio(1);                                       \
    } while (0)
#define PH_MFMA(NH_) do {                                                    \
        _Pragma("unroll")                                                    \
        for (int mi = 0; mi < 4; mi++) {                                     \
            acc[mi][3*(NH_)]   = MFMA16(aF[mi], bF[0], acc[mi][3*(NH_)]);    \
            acc[mi][3*(NH_)+1] = MFMA16(aF[mi], bF[1], acc[mi][3*(NH_)+1]);  \
            acc[mi][3*(NH_)+2] = MFMA16(aF[mi], bF[2], acc[mi][3*(NH_)+2]);  \
        }                                                                    \
    } while (0)

    f32x4 acc[4][6];
#pragma unroll
    for (int i = 0; i < 4; i++)
#pragma unroll
        for (int j = 0; j < 6; j++) acc[i][j] = (f32x4){0.f, 0.f, 0.f, 0.f};

    const int nk = 16;
    ST_A(0, 0, 0); ST_A(0, 1, 0);
    ST_B1(0, 0, 0); ST_B1(0, 1, 0); ST_B1(0, 2, 0);
    ST_A(1, 0, 1); ST_A(1, 1, 1);
    asm volatile("s_waitcnt vmcnt(4)" ::: "memory");
    __builtin_amdgcn_s_barrier();

    bf16x8 aF[4], bF[3];
    for (int m = 0; m < nk; m++) {
        const int d = m & 1, dn = d ^ 1;
#pragma unroll
        for (int mi = 0; mi < 4; mi++) aF[mi] = LDA(d, mi, 0);
        bF[0] = LDB(d, 0, 0); bF[1] = LDB(d, 1, 0); bF[2] = LDB(d, 2, 0);
        if (m + 1 < nk) { ST_B1(dn, 0, m + 1); ST_B1(dn, 1, m + 1); }
        PH_HEAD(); PH_MFMA(0);
        __builtin_amdgcn_s_setprio(0);
        __builtin_amdgcn_s_barrier();
        bF[0] = LDB(d, 3, 0); bF[1] = LDB(d, 4, 0); bF[2] = LDB(d, 5, 0);
        if (m + 1 < nk) ST_B1(dn, 2, m + 1);
        PH_HEAD(); PH_MFMA(1);
        __builtin_amdgcn_s_setprio(0);
        __builtin_amdgcn_s_barrier();
#pragma unroll
        for (int mi = 0; mi < 4; mi++) aF[mi] = LDA(d, mi, 1);
        bF[0] = LDB(d, 0, 1); bF[1] = LDB(d, 1, 1); bF[2] = LDB(d, 2, 1);
        PH_HEAD(); PH_MFMA(0);
        __builtin_amdgcn_s_setprio(0);
        __builtin_amdgcn_s_barrier();
        bF[0] = LDB(d, 3, 1); bF[1] = LDB(d, 4, 1); bF[2] = LDB(d, 5, 1);
        if (m + 2 < nk) { ST_A(d, 0, m + 2); ST_A(d, 1, m + 2); }
        PH_HEAD(); PH_MFMA(1);
        __builtin_amdgcn_s_setprio(0);
        if (m + 1 < nk) {
            if (m + 2 < nk) asm volatile("s_waitcnt vmcnt(4)" ::: "memory");
            else            asm volatile("s_waitcnt vmcnt(0)" ::: "memory");
        }
        __builtin_amdgcn_s_barrier();
    }
#undef ST_A
#undef ST_B1
#undef LDA
#undef LDB
#undef PH_HEAD
#undef PH_MFMA

#pragma unroll
    for (int mi = 0; mi < 4; mi++)
#pragma unroll
        for (int nj = 0; nj < 6; nj++) {
            const int coln = n0 + wn * 96 + nj * 16 + c16;
#pragma unroll
            for (int reg = 0; reg < 4; reg++) {
                int rowm = m0 + wm * 64 + mi * 16 + 4 * g + reg;
                Cout[(size_t)rowm * N + coln] = f2b(acc[mi][nj][reg]);
            }
        }
}

// ---------------------------------------------------------------------------
// FC2 split-K 8-phase GEMM: bf16 partials; see round-13 notes.
// ---------------------------------------------------------------------------
__global__ __launch_bounds__(512, 2) void gemm_fc2(
    const u16* __restrict__ A, const u16* __restrict__ Bt,
    u16* __restrict__ part)
{
    __shared__ u16 lds[65536];
    const int tid = threadIdx.x, l = tid & 63, w = tid >> 6;
    const int wm = w >> 2, wn = w & 3;
    const int g = l >> 4, c16 = l & 15;

    const int bid = (int)blockIdx.x;
    const int sbid = (bid & 7) * 32 + (bid >> 3);     // grid 256, bijective
    const int chunk = sbid >> 6, t = sbid & 63;
    const int m0 = (t >> 2) * 256, n0 = (t & 3) * 256;
    const int kB = chunk << 10;

    const int sr = tid >> 3;
    const int ss = ((tid & 7) ^ (sr & 7)) << 3;
    const u16* Asrc = A  + (size_t)(m0 + sr) * 4096 + kB + ss;
    const u16* Bsrc = Bt + (size_t)(n0 + sr) * 4096 + kB + ss;
    const int dst0 = tid * 8;

#define ST_A8(d_, h_, kt_) do {                                              \
        GLL16(Asrc + (size_t)((h_) * 128) * 4096 + (size_t)(kt_) * 64,       \
              &lds[(d_) * 32768 + (h_) * 8192 + dst0]);                      \
        GLL16(Asrc + (size_t)((h_) * 128 + 64) * 4096 + (size_t)(kt_) * 64,  \
              &lds[(d_) * 32768 + (h_) * 8192 + 4096 + dst0]);               \
    } while (0)
#define ST_B8(d_, h_, kt_) do {                                              \
        GLL16(Bsrc + (size_t)((h_) * 128) * 4096 + (size_t)(kt_) * 64,       \
              &lds[(d_) * 32768 + 16384 + (h_) * 8192 + dst0]);              \
        GLL16(Bsrc + (size_t)((h_) * 128 + 64) * 4096 + (size_t)(kt_) * 64,  \
              &lds[(d_) * 32768 + 16384 + (h_) * 8192 + 4096 + dst0]);       \
    } while (0)
#define LDA8(d_, mi_, s_) (*(const bf16x8*)&lds[(d_) * 32768 +               \
        (wm * 128 + (mi_) * 16 + c16) * 64 +                                  \
        ((((s_) * 4 + g) ^ ((wm * 128 + (mi_) * 16 + c16) & 7)) << 3)])
#define LDB8(d_, nj_, s_) (*(const bf16x8*)&lds[(d_) * 32768 + 16384 +       \
        (wn * 64 + (nj_) * 16 + c16) * 64 +                                   \
        ((((s_) * 4 + g) ^ ((wn * 64 + (nj_) * 16 + c16) & 7)) << 3)])
#define PH_HEAD() do {                                                       \
        __builtin_amdgcn_s_barrier();                                        \
        asm volatile("s_waitcnt lgkmcnt(0)" ::: "memory");                   \
        __builtin_amdgcn_sched_barrier(0);                                   \
        __builtin_amdgcn_s_setprio(1);                                       \
    } while (0)
#define PH_MFMA(NH_) do {                                                    \
        _Pragma("unroll")                                                    \
        for (int mi = 0; mi < 8; mi++) {                                     \
            acc[mi][2*(NH_)]   = MFMA16(aF[mi], bF[0], acc[mi][2*(NH_)]);    \
            acc[mi][2*(NH_)+1] = MFMA16(aF[mi], bF[1], acc[mi][2*(NH_)+1]);  \
        }                                                                    \
    } while (0)

    f32x4 acc[8][4];
#pragma unroll
    for (int i = 0; i < 8; i++)
#pragma unroll
        for (int j = 0; j < 4; j++) acc[i][j] = (f32x4){0.f, 0.f, 0.f, 0.f};

    const int nk = 16;
    ST_A8(0, 0, 0); ST_A8(0, 1, 0); ST_B8(0, 0, 0); ST_B8(0, 1, 0);
    ST_A8(1, 0, 1); ST_A8(1, 1, 1);
    asm volatile("s_waitcnt vmcnt(4)" ::: "memory");
    __builtin_amdgcn_s_barrier();

    bf16x8 aF[8], bF[2];
    for (int m = 0; m < nk; m++) {
        const int d = m & 1, dn = d ^ 1;
#pragma unroll
        for (int mi = 0; mi < 8; mi++) aF[mi] = LDA8(d, mi, 0);
        bF[0] = LDB8(d, 0, 0); bF[1] = LDB8(d, 1, 0);
        if (m + 1 < nk) ST_B8(dn, 0, m + 1);
        PH_HEAD(); PH_MFMA(0);
        __builtin_amdgcn_s_setprio(0);
        __builtin_amdgcn_s_barrier();
        bF[0] = LDB8(d, 2, 0); bF[1] = LDB8(d, 3, 0);
        if (m + 1 < nk) ST_B8(dn, 1, m + 1);
        PH_HEAD(); PH_MFMA(1);
        __builtin_amdgcn_s_setprio(0);
        __builtin_amdgcn_s_barrier();
#pragma unroll
        for (int mi = 0; mi < 8; mi++) aF[mi] = LDA8(d, mi, 1);
        bF[0] = LDB8(d, 0, 1); bF[1] = LDB8(d, 1, 1);
        PH_HEAD(); PH_MFMA(0);
        __builtin_amdgcn_s_setprio(0);
        __builtin_amdgcn_s_barrier();
        bF[0] = LDB8(d, 2, 1); bF[1] = LDB8(d, 3, 1);
        if (m + 2 < nk) { ST_A8(d, 0, m + 2); ST_A8(d, 1, m + 2); }
        PH_HEAD(); PH_MFMA(1);
        __builtin_amdgcn_s_setprio(0);
        if (m + 1 < nk) {
            if (m + 2 < nk) asm volatile("s_waitcnt vmcnt(4)" ::: "memory");
            else            asm volatile("s_waitcnt vmcnt(0)" ::: "memory");
        }
        __builtin_amdgcn_s_barrier();
    }
#undef ST_A8
#undef ST_B8
#undef LDA8
#undef LDB8
#undef PH_HEAD
#undef PH_MFMA

    u16* pp = part + (size_t)chunk * 4194304;
#pragma unroll
    for (int mi = 0; mi < 8; mi++)
#pragma unroll
        for (int nj = 0; nj < 4; nj++) {
            const int coln = n0 + wn * 64 + nj * 16 + c16;
#pragma unroll
            for (int reg = 0; reg < 4; reg++) {
                int rowm = m0 + wm * 128 + mi * 16 + 4 * g + reg;
                pp[(size_t)rowm * 1024 + coln] = f2b(acc[mi][nj][reg]);
            }
        }
}

// ---------------------------------------------------------------------------
// splitk_reduce (fused): out[i] = x1_bf[i] + bias[col] + sum of 4 partials.
// ---------------------------------------------------------------------------
__global__ __launch_bounds__(256) void splitk_reduce(
    const u16* __restrict__ part, const u16* __restrict__ x1,
    const float* __restrict__ bias, float* __restrict__ out)
{
    size_t i = ((size_t)blockIdx.x * 256 + threadIdx.x) * 4;
    int col = (int)(i & 1023);
    float4 bv = *(const float4*)(bias + col);
    uint2 xv = *(const uint2*)(x1 + i);
    float s0 = b2f(xv.x & 0xffffu) + bv.x;
    float s1 = b2f(xv.x >> 16)     + bv.y;
    float s2 = b2f(xv.y & 0xffffu) + bv.z;
    float s3 = b2f(xv.y >> 16)     + bv.w;
#pragma unroll
    for (int c = 0; c < 4; c++) {
        uint2 p = *(const uint2*)(part + (size_t)c * 4194304 + i);
        s0 += b2f(p.x & 0xffffu);
        s1 += b2f(p.x >> 16);
        s2 += b2f(p.y & 0xffffu);
        s3 += b2f(p.y >> 16);
    }
    float4 r; r.x = s0; r.y = s1; r.z = s2; r.w = s3;
    *(float4*)(out + i) = r;
}

// ---------------------------------------------------------------------------
// Narrow-N GEMM variant: tile 128(M)x64(N), BK=64 -> grid (N/64)x(M/128).
// ---------------------------------------------------------------------------
template<int OBF, int BIAS, int RES, int RELU>
__global__ __launch_bounds__(256) void gemm_n64(
    const u16* __restrict__ A, const u16* __restrict__ Bt,
    const float* __restrict__ bias, const float* res,
    void* Cout, int M, int N, int K)
{
    __shared__ u16 As[2][8192];    // 128 x 64
    __shared__ u16 Bs[2][4096];    // 64 x 64
    const int tid = threadIdx.x;
    const int l = tid & 63, w = tid >> 6;
    const int wr = w >> 1, wc = w & 1;
    const int g = l >> 4, c16 = l & 15;
    const int m0 = blockIdx.y * 128, n0 = blockIdx.x * 64;

    const u16* a_src[4];
    int a_dst[4];
#pragma unroll
    for (int i = 0; i < 4; i++) {
        int G = tid + 256 * i, r = G >> 3, sl = G & 7;
        a_src[i] = A + (size_t)(m0 + r) * K + ((sl ^ (r & 7)) << 3);
        a_dst[i] = G * 8;
    }
    const u16* b_src[2];
    int b_dst[2];
#pragma unroll
    for (int i = 0; i < 2; i++) {
        int G = tid + 256 * i, r = G >> 3, sl = G & 7;
        b_src[i] = Bt + (size_t)(n0 + r) * K + ((sl ^ (r & 7)) << 3);
        b_dst[i] = G * 8;
    }

    f32x4 acc[4][2];
#pragma unroll
    for (int i = 0; i < 4; i++)
#pragma unroll
        for (int j = 0; j < 2; j++) acc[i][j] = (f32x4){0.f, 0.f, 0.f, 0.f};

#define STAGE_N64(nb, k0) do {                                   \
        GLL16(a_src[0] + (k0), &As[nb][a_dst[0]]);               \
        GLL16(a_src[1] + (k0), &As[nb][a_dst[1]]);               \
        GLL16(a_src[2] + (k0), &As[nb][a_dst[2]]);               \
        GLL16(a_src[3] + (k0), &As[nb][a_dst[3]]);               \
        GLL16(b_src[0] + (k0), &Bs[nb][b_dst[0]]);               \
        GLL16(b_src[1] + (k0), &Bs[nb][b_dst[1]]);               \
    } while (0)

    STAGE_N64(0, 0);
    __syncthreads();

    int cur = 0;
    for (int k0 = 0; k0 < K; k0 += 64) {
        if (k0 + 64 < K) STAGE_N64(cur ^ 1, k0 + 64);
        const u16* AsC = As[cur];
        const u16* BsC = Bs[cur];
        bf16x8 af[4][2], bfr[2][2];
#pragma unroll
        for (int fi = 0; fi < 4; fi++) {
            int r = wr * 64 + fi * 16 + c16;
            af[fi][0] = *(const bf16x8*)&AsC[r * 64 + (((g    ) ^ (r & 7)) << 3)];
            af[fi][1] = *(const bf16x8*)&AsC[r * 64 + (((4 + g) ^ (r & 7)) << 3)];
        }
#pragma unroll
        for (int fj = 0; fj < 2; fj++) {
            int r = wc * 32 + fj * 16 + c16;
            bfr[fj][0] = *(const bf16x8*)&BsC[r * 64 + (((g    ) ^ (r & 7)) << 3)];
            bfr[fj][1] = *(const bf16x8*)&BsC[r * 64 + (((4 + g) ^ (r & 7)) << 3)];
        }
#pragma unroll
        for (int fi = 0; fi < 4; fi++)
#pragma unroll
            for (int fj = 0; fj < 2; fj++) {
                acc[fi][fj] = MFMA16(af[fi][0], bfr[fj][0], acc[fi][fj]);
                acc[fi][fj] = MFMA16(af[fi][1], bfr[fj][1], acc[fi][fj]);
            }
        __syncthreads();
        cur ^= 1;
    }
#undef STAGE_N64

#pragma unroll
    for (int fi = 0; fi < 4; fi++)
#pragma unroll
        for (int fj = 0; fj < 2; fj++) {
            int coln = n0 + wc * 32 + fj * 16 + c16;
            float bv = BIAS ? bias[coln] : 0.f;
#pragma unroll
            for (int reg = 0; reg < 4; reg++) {
                int rowm = m0 + wr * 64 + fi * 16 + 4 * g + reg;
                float v = acc[fi][fj][reg] + bv;
                if (RES) v += res[(size_t)rowm * N + coln];
                if (RELU) v = fmaxf(v, 0.f);
                if (OBF) ((u16*)Cout)[(size_t)rowm * N + coln] = f2b(v);
                else     ((float*)Cout)[(size_t)rowm * N + coln] = v;
            }
        }
}

// ---------------------------------------------------------------------------
// qkv bf16 [4096][3072] (v at col 2048+h*64+d) -> vT bf16 [(b*16+h)*64+d][2048]
// ---------------------------------------------------------------------------
__global__ __launch_bounds__(256) void v_transpose(
    const u16* __restrict__ qkv, u16* __restrict__ vT)
{
    int t0 = blockIdx.x * 64, h = blockIdx.y, b = blockIdx.z;
    __shared__ u16 t[64][72];
    int tid = threadIdx.x;
#pragma unroll
    for (int it = 0; it < 2; it++) {
        int r = it * 32 + (tid >> 3);
        int cs = (tid & 7) * 8;
        *(uint4*)&t[r][cs] =
            *(const uint4*)(qkv + (size_t)(b * 2048 + t0 + r) * 3072 + 2048 + h * 64 + cs);
    }
    __syncthreads();
    int d = tid >> 2, seg = tid & 3;
    union { u16 u[8]; uint4 q; } pk;
#pragma unroll
    for (int hq = 0; hq < 2; hq++) {
#pragma unroll
        for (int j = 0; j < 8; j++) pk.u[j] = t[seg * 16 + hq * 8 + j][d];
        *(uint4*)(vT + (size_t)((b * 16 + h) * 64 + d) * 2048 + t0 + seg * 16 + hq * 8) = pk.q;
    }
}

// ---------------------------------------------------------------------------
// MFMA flash attention (causal, no 1/sqrt(d) scale — per reference).
// QBLK=128, 8 waves = (kg k-half) x (qg 32 q-rows); see round-12 notes.
// ---------------------------------------------------------------------------
__global__ __launch_bounds__(512) void attn_mfma(
    const u16* __restrict__ qkv, const u16* __restrict__ vT,
    u16* __restrict__ outb)
{
    __shared__ u16 smem[24576];    // Ks 2x8KB | Vs 2x8KB | Ps 16KB = 48KB
    u16* KsB = smem;               // [2][4096]
    u16* VsB = smem + 8192;        // [2][4096]
    u16* PsB = smem + 16384;       // 128 q-rows x 64 k, stride 64 + XOR swz
    const int tid = threadIdx.x, l = tid & 63, w = tid >> 6;   // w 0..7
    const int g = l >> 4, c16 = l & 15;
    const int qg = w & 3, kg = w >> 2;            // q-group, k-half
    const int kg32 = kg * 32, kg64 = kg * 64;
    const int bh = blockIdx.y, b = bh >> 4, h = bh & 15;
    const int bx = (int)blockIdx.x;
    const int qt = (bh < 16) ? (15 - bx) : bx;    // balanced pair mapping
    const int r0 = qt * 128;
    const int wq0 = r0 + qg * 32;                 // wave's base q-row (32 rows)

    bf16x8 qf[2][2];
#pragma unroll
    for (int grp = 0; grp < 2; grp++) {
        const u16* qrow = qkv + (size_t)(b * 2048 + wq0 + grp * 16 + c16) * 3072 + h * 64;
        qf[grp][0] = *(const bf16x8*)(qrow + g * 8);
        qf[grp][1] = *(const bf16x8*)(qrow + 32 + g * 8);
    }

    const int kr = tid >> 3, ks = (tid & 7) ^ (kr & 7);
    const u16* kgp = qkv + (size_t)(b * 2048) * 3072 + 1024 + h * 64;
    const u16* vgp = vT + (size_t)((b * 16 + h) * 64) * 2048;

    float lrow[2] = {0.f, 0.f};
    f32x4 oacc[2][4];
#pragma unroll
    for (int grp = 0; grp < 2; grp++)
#pragma unroll
        for (int i = 0; i < 4; i++) oacc[grp][i] = (f32x4){0.f, 0.f, 0.f, 0.f};

    const int prow0 = (qg * 32 + c16) * 128;      // BYTE row base (grp0)
    const int swz   = (c16 & 7) << 4;             // 16B-chunk XOR (bytes)

#define STAGE_KV(nb, s0) do {                                                  \
        GLL16(kgp + (size_t)((s0) + kr) * 3072 + ks * 8, &KsB[(nb)*4096 + tid*8]); \
        GLL16(vgp + (size_t)kr * 2048 + (s0) + ks * 8, &VsB[(nb)*4096 + tid*8]);   \
    } while (0)

    STAGE_KV(0, 0);
    asm volatile("s_waitcnt vmcnt(0)" ::: "memory");
    __builtin_amdgcn_sched_barrier(0);
    __builtin_amdgcn_s_barrier();                 // buf0 certified for all

    const int nt = 2 * qt + 2;                    // 64-col K-tiles
    int cur = 0;
    for (int kt = 0; kt < nt; kt++) {
        if (kt + 1 < nt) STAGE_KV(cur ^ 1, (kt + 1) * 64);
        if (kt > 0) {
            if (kt + 1 < nt) asm volatile("s_waitcnt vmcnt(2)" ::: "memory");
            else             asm volatile("s_waitcnt vmcnt(0)" ::: "memory");
            __builtin_amdgcn_sched_barrier(0);
            __builtin_amdgcn_s_barrier();
        }
        const u16* KsC = &KsB[cur * 4096];
        const u16* VsC = &VsB[cur * 4096];
        const int s0 = kt * 64;

        bf16x8 kf0[2], kf1[2];
#pragma unroll
        for (int fj = 0; fj < 2; fj++) {
            int r = kg32 + fj * 16 + c16;
            kf0[fj] = *(const bf16x8*)&KsC[r * 64 + ((g       ^ (r & 7)) << 3)];
            kf1[fj] = *(const bf16x8*)&KsC[r * 64 + (((4 + g) ^ (r & 7)) << 3)];
        }
#pragma unroll
        for (int grp = 0; grp < 2; grp++) {
            f32x4 sc[2];
            sc[0] = (f32x4){0.f, 0.f, 0.f, 0.f};
            sc[1] = (f32x4){0.f, 0.f, 0.f, 0.f};
#pragma unroll
            for (int fj = 0; fj < 2; fj++) {
                sc[fj] = MFMA16(kf0[fj], qf[grp][0], sc[fj]);   // SWAPPED: S^T
                sc[fj] = MFMA16(kf1[fj], qf[grp][1], sc[fj]);
            }
            const int qgl = wq0 + grp * 16 + c16;  // this lane's q row
            if (s0 + kg32 + 31 > wq0 + grp * 16) { // causal frontier possible
#pragma unroll
                for (int fj = 0; fj < 2; fj++)
#pragma unroll
                    for (int reg = 0; reg < 4; reg++)
                        if (s0 + kg32 + fj * 16 + 4 * g + reg > qgl)
                            sc[fj][reg] = -1e30f;
            }
#pragma unroll
            for (int fj = 0; fj < 2; fj++) {
                float p0 = __expf(sc[fj][0]);
                float p1 = __expf(sc[fj][1]);
                float p2 = __expf(sc[fj][2]);
                float p3 = __expf(sc[fj][3]);
                lrow[grp] += (p0 + p1) + (p2 + p3);
                uint2 pk;
                pk.x = cvtpk(p0, p1);
                pk.y = cvtpk(p2, p3);
                *(uint2*)((char*)PsB + prow0 + grp * 2048 +
                          ((kg64 + fj * 32 + 8 * g) ^ swz)) = pk;
            }
        }
        bf16x8 pa0 = *(const bf16x8*)((const char*)PsB + prow0 +
                                      ((kg64 + 16 * g) ^ swz));
        bf16x8 pa1 = *(const bf16x8*)((const char*)PsB + prow0 + 2048 +
                                      ((kg64 + 16 * g) ^ swz));
#pragma unroll
        for (int fd = 0; fd < 4; fd++) {
            int r = fd * 16 + c16;
            bf16x8 vf = *(const bf16x8*)&VsC[r * 64 + (((4 * kg + g) ^ (r & 7)) << 3)];
            oacc[0][fd] = MFMA16(pa0, vf, oacc[0][fd]);
            oacc[1][fd] = MFMA16(pa1, vf, oacc[1][fd]);
        }
        __builtin_amdgcn_s_barrier();
        cur ^= 1;
    }
#undef STAGE_KV

#pragma unroll
    for (int grp = 0; grp < 2; grp++) {
        lrow[grp] += __shfl_xor(lrow[grp], 16);
        lrow[grp] += __shfl_xor(lrow[grp], 32);
    }

    __syncthreads();
    float* scr = (float*)smem;                     // 48KB >= 4*64*36*4B
    const int sbase = qg * 2304 + l * 36;          // 16B-aligned per lane
    if (kg == 1) {
#pragma unroll
        for (int grp = 0; grp < 2; grp++) {
#pragma unroll
            for (int fd = 0; fd < 4; fd++)
                *(f32x4*)&scr[sbase + grp * 16 + fd * 4] = oacc[grp][fd];
            scr[sbase + 32 + grp] = lrow[grp];
        }
    }
    __syncthreads();
    if (kg == 0) {
#pragma unroll
        for (int grp = 0; grp < 2; grp++) {
#pragma unroll
            for (int fd = 0; fd < 4; fd++)
                oacc[grp][fd] += *(const f32x4*)&scr[sbase + grp * 16 + fd * 4];
            float lr = lrow[grp] + scr[sbase + 32 + grp];
#pragma unroll
            for (int reg = 0; reg < 4; reg++) {
                float ls = __shfl(lr, 4 * g + reg);   // lsum of q-row 4g+reg
                float inv = 1.0f / ls;
                int t = wq0 + grp * 16 + 4 * g + reg;
                u16* op = outb + (size_t)(b * 2048 + t) * 1024 + h * 64;
#pragma unroll
                for (int fd = 0; fd < 4; fd++)
                    op[fd * 16 + c16] = f2b(oacc[grp][fd][reg] * inv);
            }
        }
    }
}

// ---------------------------------------------------------------------------
extern "C" void kernel_launch(void* const* d_in, const int* in_sizes, int n_in,
                              void* d_out, int out_size, void* d_ws, size_t ws_size,
                              hipStream_t stream) {
    const float* x     = (const float*)d_in[0];
    const float* ln1w  = (const float*)d_in[1];
    const float* ln1b  = (const float*)d_in[2];
    const float* Wq    = (const float*)d_in[3];
    const float* Wk    = (const float*)d_in[4];
    const float* Wv    = (const float*)d_in[5];
    const float* projw = (const float*)d_in[6];
    const float* projb = (const float*)d_in[7];
    const float* ln2w  = (const float*)d_in[8];
    const float* ln2b  = (const float*)d_in[9];
    const float* fc1w  = (const float*)d_in[10];
    const float* fc1b  = (const float*)d_in[11];
    const float* fc2w  = (const float*)d_in[12];
    const float* fc2b  = (const float*)d_in[13];
    float* out = (float*)d_out;

    u16* h_bf    = (u16*)d_ws;                 // 4096*1024
    u16* qkv_bf  = h_bf    + 4194304;          // 4096*3072
    u16* vTb     = qkv_bf  + 12582912;         // 2048*2048
    u16* attn_bf = vTb     + 4194304;          // 4096*1024
    u16* ff1_bf  = attn_bf + 4194304;          // 4096*4096
    u16* WtQKV   = ff1_bf  + 16777216;         // 3072*1024
    u16* WtP     = WtQKV   + 3145728;          // 1024*1024
    u16* Wt1     = WtP     + 1048576;          // 4096*1024
    u16* Wt2     = Wt1     + 4194304;          // 1024*4096
    u16* x1_bf   = Wt2     + 4194304;          // 4096*1024 (x + sa, bf16)
    u16* fc2p = (u16*)d_ws;                    // FC2 partials reuse dead region

    repack_all<<<dim3(3072), 256, 0, stream>>>(
        Wq, Wk, Wv, WtQKV, projw, WtP, fc1w, Wt1, fc2w, Wt2);

    ln_bf16<<<1024, 256, 0, stream>>>(x, ln1w, ln1b, h_bf);
    gemm_qkv<<<dim3(256), 512, 0, stream>>>(h_bf, WtQKV, qkv_bf);
    v_transpose<<<dim3(32, 16, 2), 256, 0, stream>>>(qkv_bf, vTb);
    attn_mfma<<<dim3(16, 32), 512, 0, stream>>>(qkv_bf, vTb, attn_bf);
    gemm_n64<1, 1, 1, 0><<<dim3(16, 32), 256, 0, stream>>>(
        attn_bf, WtP, projb, x, x1_bf, Mn, 1024, 1024);
    ln_bf16_b<<<1024, 256, 0, stream>>>(x1_bf, ln2w, ln2b, h_bf);
    gemm_fc1<<<dim3(512), 512, 0, stream>>>(h_bf, Wt1, fc1b, ff1_bf);
    gemm_fc2<<<dim3(256), 512, 0, stream>>>(ff1_bf, Wt2, fc2p);
    splitk_reduce<<<dim3(4096), 256, 0, stream>>>(fc2p, x1_bf, fc2b, out);
}

// Round 18
// 198.747 us; speedup vs baseline: 1.0222x; 1.0222x over previous
//
#include <hip/hip_runtime.h>
#include <hip/hip_bf16.h>

#define Bn 2
#define Tn 2048
#define Cn 1024
#define Hn 16
#define HSn 64
#define Mn (Bn*Tn)          // 4096
#define LN_EPS 1e-5f

typedef unsigned short u16;
typedef __attribute__((ext_vector_type(8))) short bf16x8;   // 8 bf16 = 4 VGPRs
typedef __attribute__((ext_vector_type(4))) float f32x4;

#define MFMA16(a,b,c) __builtin_amdgcn_mfma_f32_16x16x32_bf16(a, b, c, 0, 0, 0)
#define GLL16(g,l) __builtin_amdgcn_global_load_lds( \
    (const __attribute__((address_space(1))) void*)(g), \
    (__attribute__((address_space(3))) void*)(l), 16, 0, 0)

__device__ __forceinline__ u16 f2b(float f) {               // f32 -> bf16 RNE
    unsigned int u = __float_as_uint(f);
    unsigned int r = (u + 0x7FFFu + ((u >> 16) & 1u)) >> 16;
    return (u16)r;
}
__device__ __forceinline__ float b2f(unsigned u) {          // bf16 -> f32
    return __uint_as_float(u << 16);
}
__device__ __forceinline__ unsigned cvtpk(float lo, float hi) { // [hi|lo] bf16x2
    unsigned r;
    asm("v_cvt_pk_bf16_f32 %0, %1, %2" : "=v"(r) : "v"(lo), "v"(hi));
    return r;
}

// ---------------------------------------------------------------------------
// Shared 64x64 transpose-convert tile body (f32 in -> bf16 out^T).
// ---------------------------------------------------------------------------
__device__ __forceinline__ void trans_tile(
    const float* __restrict__ in, u16* __restrict__ out,
    int R, int C, int r0, int c0c, float (*t)[68], int tid)
{
#pragma unroll
    for (int it = 0; it < 4; it++) {
        int r = it * 16 + (tid >> 4);
        *(float4*)&t[r][(tid & 15) * 4] =
            *(const float4*)(in + (size_t)(r0 + r) * C + c0c + (tid & 15) * 4);
    }
    __syncthreads();
    int c = tid >> 2, seg = tid & 3;
    union { u16 u[8]; uint4 q; } pk;
#pragma unroll
    for (int hq = 0; hq < 2; hq++) {
#pragma unroll
        for (int j = 0; j < 8; j++) pk.u[j] = f2b(t[seg * 16 + hq * 8 + j][c]);
        *(uint4*)(out + (size_t)(c0c + c) * R + r0 + seg * 16 + hq * 8) = pk.q;
    }
}

// ---------------------------------------------------------------------------
// Fused weight repack: all four weight transposes in ONE launch (3072 blocks).
// [0,768): Wq/Wk/Wv [H][C][64] -> WtQKV^T [3072][1024]
// [768,1024): projw 1024x1024 -> WtP^T
// [1024,2048): fc1w 1024x4096 -> Wt1^T [4096][1024]
// [2048,3072): fc2w 4096x1024 -> Wt2^T [1024][4096]
// ---------------------------------------------------------------------------
__global__ __launch_bounds__(256) void repack_all(
    const float* __restrict__ Wq, const float* __restrict__ Wk,
    const float* __restrict__ Wv, u16* __restrict__ WtQKV,
    const float* __restrict__ projw, u16* __restrict__ WtP,
    const float* __restrict__ fc1w, u16* __restrict__ Wt1,
    const float* __restrict__ fc2w, u16* __restrict__ Wt2)
{
    __shared__ float t[64][68];
    const int bid = (int)blockIdx.x, tid = threadIdx.x;
    if (bid < 768) {
        int z = bid >> 8, rem = bid & 255, h = rem >> 4, c0 = (rem & 15) * 64;
        const float* in = (z == 0 ? Wq : z == 1 ? Wk : Wv) + (size_t)h * 65536;
        u16* outb = WtQKV + (size_t)(z * 1024 + h * 64) * 1024;
        trans_tile(in, outb, 1024, 64, c0, 0, t, tid);
    } else if (bid < 1024) {
        int idx = bid - 768, bx = idx & 15, by = idx >> 4;
        trans_tile(projw, WtP, 1024, 1024, by * 64, bx * 64, t, tid);
    } else if (bid < 2048) {
        int idx = bid - 1024, bx = idx & 63, by = idx >> 6;
        trans_tile(fc1w, Wt1, 1024, 4096, by * 64, bx * 64, t, tid);
    } else {
        int idx = bid - 2048, bx = idx & 15, by = idx >> 4;
        trans_tile(fc2w, Wt2, 4096, 1024, by * 64, bx * 64, t, tid);
    }
}

// ---------------------------------------------------------------------------
// LayerNorm f32 in -> bf16 out. One wave per row.
// ---------------------------------------------------------------------------
__global__ __launch_bounds__(256) void ln_bf16(
    const float* __restrict__ x, const float* __restrict__ w,
    const float* __restrict__ bvec, u16* __restrict__ out)
{
    int row  = blockIdx.x * 4 + (threadIdx.x >> 6);
    int lane = threadIdx.x & 63;
    const float* xr = x + (size_t)row * Cn;
    float4 v[4];
    float s = 0.f, sq = 0.f;
#pragma unroll
    for (int i = 0; i < 4; i++) {
        v[i] = *(const float4*)(xr + lane * 4 + i * 256);
        s  += v[i].x + v[i].y + v[i].z + v[i].w;
        sq += v[i].x * v[i].x + v[i].y * v[i].y + v[i].z * v[i].z + v[i].w * v[i].w;
    }
#pragma unroll
    for (int off = 1; off < 64; off <<= 1) {
        s  += __shfl_xor(s, off);
        sq += __shfl_xor(sq, off);
    }
    float mu   = s * (1.f / Cn);
    float var  = sq * (1.f / Cn) - mu * mu;
    float rstd = rsqrtf(var + LN_EPS);
    u16* orow = out + (size_t)row * Cn;
#pragma unroll
    for (int i = 0; i < 4; i++) {
        float4 w4 = *(const float4*)(w    + lane * 4 + i * 256);
        float4 b4 = *(const float4*)(bvec + lane * 4 + i * 256);
        union { u16 u[4]; uint2 q; } pk;
        pk.u[0] = f2b((v[i].x - mu) * rstd * w4.x + b4.x);
        pk.u[1] = f2b((v[i].y - mu) * rstd * w4.y + b4.y);
        pk.u[2] = f2b((v[i].z - mu) * rstd * w4.z + b4.z);
        pk.u[3] = f2b((v[i].w - mu) * rstd * w4.w + b4.w);
        *(uint2*)(orow + lane * 4 + i * 256) = pk.q;
    }
}

// ---------------------------------------------------------------------------
// LayerNorm bf16 in -> bf16 out. One wave per row (16 elems/lane, contiguous).
// ---------------------------------------------------------------------------
__global__ __launch_bounds__(256) void ln_bf16_b(
    const u16* __restrict__ x, const float* __restrict__ w,
    const float* __restrict__ bvec, u16* __restrict__ out)
{
    int row  = blockIdx.x * 4 + (threadIdx.x >> 6);
    int lane = threadIdx.x & 63;
    const u16* xr = x + (size_t)row * Cn + lane * 16;
    float v[16];
    float s = 0.f, sq = 0.f;
#pragma unroll
    for (int i = 0; i < 2; i++) {
        uint4 q = *(const uint4*)(xr + i * 8);
        float* vv = v + i * 8;
        vv[0] = b2f(q.x & 0xffffu); vv[1] = b2f(q.x >> 16);
        vv[2] = b2f(q.y & 0xffffu); vv[3] = b2f(q.y >> 16);
        vv[4] = b2f(q.z & 0xffffu); vv[5] = b2f(q.z >> 16);
        vv[6] = b2f(q.w & 0xffffu); vv[7] = b2f(q.w >> 16);
    }
#pragma unroll
    for (int j = 0; j < 16; j++) { s += v[j]; sq += v[j] * v[j]; }
#pragma unroll
    for (int off = 1; off < 64; off <<= 1) {
        s  += __shfl_xor(s, off);
        sq += __shfl_xor(sq, off);
    }
    float mu   = s * (1.f / Cn);
    float var  = sq * (1.f / Cn) - mu * mu;
    float rstd = rsqrtf(var + LN_EPS);
    u16* orow = out + (size_t)row * Cn + lane * 16;
#pragma unroll
    for (int i = 0; i < 2; i++) {
        union { u16 u[8]; uint4 q; } pk;
#pragma unroll
        for (int j = 0; j < 8; j++) {
            int col = lane * 16 + i * 8 + j;
            pk.u[j] = f2b((v[i * 8 + j] - mu) * rstd * w[col] + bvec[col]);
        }
        *(uint4*)(orow + i * 8) = pk.q;
    }
}

// ---------------------------------------------------------------------------
// 8-phase 256x256 MFMA GEMM (T2+T3+T4+T5 port, plain HIP). Used for FC1.
// ---------------------------------------------------------------------------
template<int OBF, int BIAS, int RELU>
__global__ __launch_bounds__(512, 2) void gemm_8ph(
    const u16* __restrict__ A, const u16* __restrict__ Bt,
    const float* __restrict__ bias, void* Cout,
    int M, int N, int K, int NT)
{
    __shared__ u16 lds[65536];                 // 128 KiB
    const int tid = threadIdx.x, l = tid & 63, w = tid >> 6;
    const int wm = w >> 2, wn = w & 3;
    const int g = l >> 4, c16 = l & 15;

    const int nwg = (int)gridDim.x, cpx = nwg >> 3;
    const int bid = (int)blockIdx.x;
    const int sbid = (bid & 7) * cpx + (bid >> 3);
    const int m0 = (sbid / NT) * 256, n0 = (sbid % NT) * 256;

    const int sr = tid >> 3;
    const int ss = ((tid & 7) ^ (sr & 7)) << 3;
    const u16* Asrc = A  + (size_t)(m0 + sr) * K + ss;
    const u16* Bsrc = Bt + (size_t)(n0 + sr) * K + ss;
    const int dst0 = tid * 8;

#define ST_A8(d_, h_, kt_) do {                                              \
        GLL16(Asrc + (size_t)((h_) * 128) * K + (size_t)(kt_) * 64,          \
              &lds[(d_) * 32768 + (h_) * 8192 + dst0]);                      \
        GLL16(Asrc + (size_t)((h_) * 128 + 64) * K + (size_t)(kt_) * 64,     \
              &lds[(d_) * 32768 + (h_) * 8192 + 4096 + dst0]);               \
    } while (0)
#define ST_B8(d_, h_, kt_) do {                                              \
        GLL16(Bsrc + (size_t)((h_) * 128) * K + (size_t)(kt_) * 64,          \
              &lds[(d_) * 32768 + 16384 + (h_) * 8192 + dst0]);              \
        GLL16(Bsrc + (size_t)((h_) * 128 + 64) * K + (size_t)(kt_) * 64,     \
              &lds[(d_) * 32768 + 16384 + (h_) * 8192 + 4096 + dst0]);       \
    } while (0)
#define LDA8(d_, mi_, s_) (*(const bf16x8*)&lds[(d_) * 32768 +               \
        (wm * 128 + (mi_) * 16 + c16) * 64 +                                  \
        ((((s_) * 4 + g) ^ ((wm * 128 + (mi_) * 16 + c16) & 7)) << 3)])
#define LDB8(d_, nj_, s_) (*(const bf16x8*)&lds[(d_) * 32768 + 16384 +       \
        (wn * 64 + (nj_) * 16 + c16) * 64 +                                   \
        ((((s_) * 4 + g) ^ ((wn * 64 + (nj_) * 16 + c16) & 7)) << 3)])
#define PH_HEAD() do {                                                       \
        __builtin_amdgcn_s_barrier();                                        \
        asm volatile("s_waitcnt lgkmcnt(0)" ::: "memory");                   \
        __builtin_amdgcn_sched_barrier(0);                                   \
        __builtin_amdgcn_s_setprio(1);                                       \
    } while (0)
#define PH_MFMA(NH_) do {                                                    \
        _Pragma("unroll")                                                    \
        for (int mi = 0; mi < 8; mi++) {                                     \
            acc[mi][2*(NH_)]   = MFMA16(aF[mi], bF[0], acc[mi][2*(NH_)]);    \
            acc[mi][2*(NH_)+1] = MFMA16(aF[mi], bF[1], acc[mi][2*(NH_)+1]);  \
        }                                                                    \
    } while (0)

    f32x4 acc[8][4];
#pragma unroll
    for (int i = 0; i < 8; i++)
#pragma unroll
        for (int j = 0; j < 4; j++) acc[i][j] = (f32x4){0.f, 0.f, 0.f, 0.f};

    const int nk = K >> 6;
    ST_A8(0, 0, 0); ST_A8(0, 1, 0); ST_B8(0, 0, 0); ST_B8(0, 1, 0);
    ST_A8(1, 0, 1); ST_A8(1, 1, 1);
    asm volatile("s_waitcnt vmcnt(4)" ::: "memory");
    __builtin_amdgcn_s_barrier();

    bf16x8 aF[8], bF[2];
    for (int m = 0; m < nk; m++) {
        const int d = m & 1, dn = d ^ 1;
#pragma unroll
        for (int mi = 0; mi < 8; mi++) aF[mi] = LDA8(d, mi, 0);
        bF[0] = LDB8(d, 0, 0); bF[1] = LDB8(d, 1, 0);
        if (m + 1 < nk) ST_B8(dn, 0, m + 1);
        PH_HEAD(); PH_MFMA(0);
        __builtin_amdgcn_s_setprio(0);
        __builtin_amdgcn_s_barrier();
        bF[0] = LDB8(d, 2, 0); bF[1] = LDB8(d, 3, 0);
        if (m + 1 < nk) ST_B8(dn, 1, m + 1);
        PH_HEAD(); PH_MFMA(1);
        __builtin_amdgcn_s_setprio(0);
        __builtin_amdgcn_s_barrier();
#pragma unroll
        for (int mi = 0; mi < 8; mi++) aF[mi] = LDA8(d, mi, 1);
        bF[0] = LDB8(d, 0, 1); bF[1] = LDB8(d, 1, 1);
        PH_HEAD(); PH_MFMA(0);
        __builtin_amdgcn_s_setprio(0);
        __builtin_amdgcn_s_barrier();
        bF[0] = LDB8(d, 2, 1); bF[1] = LDB8(d, 3, 1);
        if (m + 2 < nk) { ST_A8(d, 0, m + 2); ST_A8(d, 1, m + 2); }
        PH_HEAD(); PH_MFMA(1);
        __builtin_amdgcn_s_setprio(0);
        if (m + 1 < nk) {
            if (m + 2 < nk) asm volatile("s_waitcnt vmcnt(4)" ::: "memory");
            else            asm volatile("s_waitcnt vmcnt(0)" ::: "memory");
        }
        __builtin_amdgcn_s_barrier();
    }
#undef ST_A8
#undef ST_B8
#undef LDA8
#undef LDB8
#undef PH_HEAD
#undef PH_MFMA

#pragma unroll
    for (int mi = 0; mi < 8; mi++)
#pragma unroll
        for (int nj = 0; nj < 4; nj++) {
            const int coln = n0 + wn * 64 + nj * 16 + c16;
            float bv = BIAS ? bias[coln] : 0.f;
#pragma unroll
            for (int reg = 0; reg < 4; reg++) {
                int rowm = m0 + wm * 128 + mi * 16 + 4 * g + reg;
                float v = acc[mi][nj][reg] + bv;
                if (RELU) v = fmaxf(v, 0.f);
                if (OBF) ((u16*)Cout)[(size_t)rowm * N + coln] = f2b(v);
                else     ((float*)Cout)[(size_t)rowm * N + coln] = v;
            }
        }
}

// ---------------------------------------------------------------------------
// QKV 8-phase GEMM, tile 256(M) x 192(N), BK=64: grid 16x16 = 256 blocks.
// ---------------------------------------------------------------------------
__global__ __launch_bounds__(512, 1) void gemm_qkv(
    const u16* __restrict__ A, const u16* __restrict__ Bt,
    u16* __restrict__ Cout)
{
    __shared__ u16 lds[57344];                 // A 2x32KB | B 2x24KB = 112 KiB
    const int tid = threadIdx.x, l = tid & 63, w = tid >> 6;
    const int wm = w >> 1, wn = w & 1;         // 4M x 2N waves
    const int g = l >> 4, c16 = l & 15;
    const int K = 1024, N = 3072;

    const int bid = (int)blockIdx.x;
    const int sbid = (bid & 7) * 32 + (bid >> 3);      // grid 256, bijective
    const int m0 = (sbid >> 4) * 256, n0 = (sbid & 15) * 192;

    const int sr = tid >> 3;
    const int ss = ((tid & 7) ^ (sr & 7)) << 3;
    const u16* Asrc = A  + (size_t)(m0 + sr) * K + ss;
    const u16* Bsrc = Bt + (size_t)(n0 + sr) * K + ss;
    const int dst0 = tid * 8;

#define ST_A(d_, h_, kt_) do {                                               \
        GLL16(Asrc + (size_t)((h_) * 128) * K + (size_t)(kt_) * 64,          \
              &lds[(d_) * 16384 + (h_) * 8192 + dst0]);                      \
        GLL16(Asrc + (size_t)((h_) * 128 + 64) * K + (size_t)(kt_) * 64,     \
              &lds[(d_) * 16384 + (h_) * 8192 + 4096 + dst0]);               \
    } while (0)
#define ST_B1(d_, seg_, kt_)                                                 \
        GLL16(Bsrc + (size_t)((seg_) * 64) * K + (size_t)(kt_) * 64,         \
              &lds[32768 + (d_) * 12288 + (seg_) * 4096 + dst0])
#define LDA(d_, mi_, s_) (*(const bf16x8*)&lds[(d_) * 16384 +                \
        (wm * 64 + (mi_) * 16 + c16) * 64 +                                   \
        ((((s_) * 4 + g) ^ ((wm * 64 + (mi_) * 16 + c16) & 7)) << 3)])
#define LDB(d_, nj_, s_) (*(const bf16x8*)&lds[32768 + (d_) * 12288 +        \
        (wn * 96 + (nj_) * 16 + c16) * 64 +                                   \
        ((((s_) * 4 + g) ^ ((wn * 96 + (nj_) * 16 + c16) & 7)) << 3)])
#define PH_HEAD() do {                                                       \
        __builtin_amdgcn_s_barrier();                                        \
        asm volatile("s_waitcnt lgkmcnt(0)" ::: "memory");                   \
        __builtin_amdgcn_sched_barrier(0);                                   \
        __builtin_amdgcn_s_setprio(1);                                       \
    } while (0)
#define PH_MFMA(NH_) do {                                                    \
        _Pragma("unroll")                                                    \
        for (int mi = 0; mi < 4; mi++) {                                     \
            acc[mi][3*(NH_)]   = MFMA16(aF[mi], bF[0], acc[mi][3*(NH_)]);    \
            acc[mi][3*(NH_)+1] = MFMA16(aF[mi], bF[1], acc[mi][3*(NH_)+1]);  \
            acc[mi][3*(NH_)+2] = MFMA16(aF[mi], bF[2], acc[mi][3*(NH_)+2]);  \
        }                                                                    \
    } while (0)

    f32x4 acc[4][6];
#pragma unroll
    for (int i = 0; i < 4; i++)
#pragma unroll
        for (int j = 0; j < 6; j++) acc[i][j] = (f32x4){0.f, 0.f, 0.f, 0.f};

    const int nk = 16;
    ST_A(0, 0, 0); ST_A(0, 1, 0);
    ST_B1(0, 0, 0); ST_B1(0, 1, 0); ST_B1(0, 2, 0);
    ST_A(1, 0, 1); ST_A(1, 1, 1);
    asm volatile("s_waitcnt vmcnt(4)" ::: "memory");
    __builtin_amdgcn_s_barrier();

    bf16x8 aF[4], bF[3];
    for (int m = 0; m < nk; m++) {
        const int d = m & 1, dn = d ^ 1;
#pragma unroll
        for (int mi = 0; mi < 4; mi++) aF[mi] = LDA(d, mi, 0);
        bF[0] = LDB(d, 0, 0); bF[1] = LDB(d, 1, 0); bF[2] = LDB(d, 2, 0);
        if (m + 1 < nk) { ST_B1(dn, 0, m + 1); ST_B1(dn, 1, m + 1); }
        PH_HEAD(); PH_MFMA(0);
        __builtin_amdgcn_s_setprio(0);
        __builtin_amdgcn_s_barrier();
        bF[0] = LDB(d, 3, 0); bF[1] = LDB(d, 4, 0); bF[2] = LDB(d, 5, 0);
        if (m + 1 < nk) ST_B1(dn, 2, m + 1);
        PH_HEAD(); PH_MFMA(1);
        __builtin_amdgcn_s_setprio(0);
        __builtin_amdgcn_s_barrier();
#pragma unroll
        for (int mi = 0; mi < 4; mi++) aF[mi] = LDA(d, mi, 1);
        bF[0] = LDB(d, 0, 1); bF[1] = LDB(d, 1, 1); bF[2] = LDB(d, 2, 1);
        PH_HEAD(); PH_MFMA(0);
        __builtin_amdgcn_s_setprio(0);
        __builtin_amdgcn_s_barrier();
        bF[0] = LDB(d, 3, 1); bF[1] = LDB(d, 4, 1); bF[2] = LDB(d, 5, 1);
        if (m + 2 < nk) { ST_A(d, 0, m + 2); ST_A(d, 1, m + 2); }
        PH_HEAD(); PH_MFMA(1);
        __builtin_amdgcn_s_setprio(0);
        if (m + 1 < nk) {
            if (m + 2 < nk) asm volatile("s_waitcnt vmcnt(4)" ::: "memory");
            else            asm volatile("s_waitcnt vmcnt(0)" ::: "memory");
        }
        __builtin_amdgcn_s_barrier();
    }
#undef ST_A
#undef ST_B1
#undef LDA
#undef LDB
#undef PH_HEAD
#undef PH_MFMA

#pragma unroll
    for (int mi = 0; mi < 4; mi++)
#pragma unroll
        for (int nj = 0; nj < 6; nj++) {
            const int coln = n0 + wn * 96 + nj * 16 + c16;
#pragma unroll
            for (int reg = 0; reg < 4; reg++) {
                int rowm = m0 + wm * 64 + mi * 16 + 4 * g + reg;
                Cout[(size_t)rowm * N + coln] = f2b(acc[mi][nj][reg]);
            }
        }
}

// ---------------------------------------------------------------------------
// FC2 split-K 8-phase GEMM: bf16 partials; bias/residual in splitk_reduce.
// ---------------------------------------------------------------------------
__global__ __launch_bounds__(512, 2) void gemm_fc2(
    const u16* __restrict__ A, const u16* __restrict__ Bt,
    u16* __restrict__ part)
{
    __shared__ u16 lds[65536];
    const int tid = threadIdx.x, l = tid & 63, w = tid >> 6;
    const int wm = w >> 2, wn = w & 3;
    const int g = l >> 4, c16 = l & 15;

    const int bid = (int)blockIdx.x;
    const int sbid = (bid & 7) * 32 + (bid >> 3);     // grid 256, bijective
    const int chunk = sbid >> 6, t = sbid & 63;
    const int m0 = (t >> 2) * 256, n0 = (t & 3) * 256;
    const int kB = chunk << 10;

    const int sr = tid >> 3;
    const int ss = ((tid & 7) ^ (sr & 7)) << 3;
    const u16* Asrc = A  + (size_t)(m0 + sr) * 4096 + kB + ss;
    const u16* Bsrc = Bt + (size_t)(n0 + sr) * 4096 + kB + ss;
    const int dst0 = tid * 8;

#define ST_A8(d_, h_, kt_) do {                                              \
        GLL16(Asrc + (size_t)((h_) * 128) * 4096 + (size_t)(kt_) * 64,       \
              &lds[(d_) * 32768 + (h_) * 8192 + dst0]);                      \
        GLL16(Asrc + (size_t)((h_) * 128 + 64) * 4096 + (size_t)(kt_) * 64,  \
              &lds[(d_) * 32768 + (h_) * 8192 + 4096 + dst0]);               \
    } while (0)
#define ST_B8(d_, h_, kt_) do {                                              \
        GLL16(Bsrc + (size_t)((h_) * 128) * 4096 + (size_t)(kt_) * 64,       \
              &lds[(d_) * 32768 + 16384 + (h_) * 8192 + dst0]);              \
        GLL16(Bsrc + (size_t)((h_) * 128 + 64) * 4096 + (size_t)(kt_) * 64,  \
              &lds[(d_) * 32768 + 16384 + (h_) * 8192 + 4096 + dst0]);       \
    } while (0)
#define LDA8(d_, mi_, s_) (*(const bf16x8*)&lds[(d_) * 32768 +               \
        (wm * 128 + (mi_) * 16 + c16) * 64 +                                  \
        ((((s_) * 4 + g) ^ ((wm * 128 + (mi_) * 16 + c16) & 7)) << 3)])
#define LDB8(d_, nj_, s_) (*(const bf16x8*)&lds[(d_) * 32768 + 16384 +       \
        (wn * 64 + (nj_) * 16 + c16) * 64 +                                   \
        ((((s_) * 4 + g) ^ ((wn * 64 + (nj_) * 16 + c16) & 7)) << 3)])
#define PH_HEAD() do {                                                       \
        __builtin_amdgcn_s_barrier();                                        \
        asm volatile("s_waitcnt lgkmcnt(0)" ::: "memory");                   \
        __builtin_amdgcn_sched_barrier(0);                                   \
        __builtin_amdgcn_s_setprio(1);                                       \
    } while (0)
#define PH_MFMA(NH_) do {                                                    \
        _Pragma("unroll")                                                    \
        for (int mi = 0; mi < 8; mi++) {                                     \
            acc[mi][2*(NH_)]   = MFMA16(aF[mi], bF[0], acc[mi][2*(NH_)]);    \
            acc[mi][2*(NH_)+1] = MFMA16(aF[mi], bF[1], acc[mi][2*(NH_)+1]);  \
        }                                                                    \
    } while (0)

    f32x4 acc[8][4];
#pragma unroll
    for (int i = 0; i < 8; i++)
#pragma unroll
        for (int j = 0; j < 4; j++) acc[i][j] = (f32x4){0.f, 0.f, 0.f, 0.f};

    const int nk = 16;
    ST_A8(0, 0, 0); ST_A8(0, 1, 0); ST_B8(0, 0, 0); ST_B8(0, 1, 0);
    ST_A8(1, 0, 1); ST_A8(1, 1, 1);
    asm volatile("s_waitcnt vmcnt(4)" ::: "memory");
    __builtin_amdgcn_s_barrier();

    bf16x8 aF[8], bF[2];
    for (int m = 0; m < nk; m++) {
        const int d = m & 1, dn = d ^ 1;
#pragma unroll
        for (int mi = 0; mi < 8; mi++) aF[mi] = LDA8(d, mi, 0);
        bF[0] = LDB8(d, 0, 0); bF[1] = LDB8(d, 1, 0);
        if (m + 1 < nk) ST_B8(dn, 0, m + 1);
        PH_HEAD(); PH_MFMA(0);
        __builtin_amdgcn_s_setprio(0);
        __builtin_amdgcn_s_barrier();
        bF[0] = LDB8(d, 2, 0); bF[1] = LDB8(d, 3, 0);
        if (m + 1 < nk) ST_B8(dn, 1, m + 1);
        PH_HEAD(); PH_MFMA(1);
        __builtin_amdgcn_s_setprio(0);
        __builtin_amdgcn_s_barrier();
#pragma unroll
        for (int mi = 0; mi < 8; mi++) aF[mi] = LDA8(d, mi, 1);
        bF[0] = LDB8(d, 0, 1); bF[1] = LDB8(d, 1, 1);
        PH_HEAD(); PH_MFMA(0);
        __builtin_amdgcn_s_setprio(0);
        __builtin_amdgcn_s_barrier();
        bF[0] = LDB8(d, 2, 1); bF[1] = LDB8(d, 3, 1);
        if (m + 2 < nk) { ST_A8(d, 0, m + 2); ST_A8(d, 1, m + 2); }
        PH_HEAD(); PH_MFMA(1);
        __builtin_amdgcn_s_setprio(0);
        if (m + 1 < nk) {
            if (m + 2 < nk) asm volatile("s_waitcnt vmcnt(4)" ::: "memory");
            else            asm volatile("s_waitcnt vmcnt(0)" ::: "memory");
        }
        __builtin_amdgcn_s_barrier();
    }
#undef ST_A8
#undef ST_B8
#undef LDA8
#undef LDB8
#undef PH_HEAD
#undef PH_MFMA

    u16* pp = part + (size_t)chunk * 4194304;
#pragma unroll
    for (int mi = 0; mi < 8; mi++)
#pragma unroll
        for (int nj = 0; nj < 4; nj++) {
            const int coln = n0 + wn * 64 + nj * 16 + c16;
#pragma unroll
            for (int reg = 0; reg < 4; reg++) {
                int rowm = m0 + wm * 128 + mi * 16 + 4 * g + reg;
                pp[(size_t)rowm * 1024 + coln] = f2b(acc[mi][nj][reg]);
            }
        }
}

// ---------------------------------------------------------------------------
// splitk_reduce (fused): out[i] = x1_bf[i] + bias[col] + sum of 4 partials.
// Full overwrite of d_out (no RMW).
// ---------------------------------------------------------------------------
__global__ __launch_bounds__(256) void splitk_reduce(
    const u16* __restrict__ part, const u16* __restrict__ x1,
    const float* __restrict__ bias, float* __restrict__ out)
{
    size_t i = ((size_t)blockIdx.x * 256 + threadIdx.x) * 4;
    int col = (int)(i & 1023);
    float4 bv = *(const float4*)(bias + col);
    uint2 xv = *(const uint2*)(x1 + i);
    float s0 = b2f(xv.x & 0xffffu) + bv.x;
    float s1 = b2f(xv.x >> 16)     + bv.y;
    float s2 = b2f(xv.y & 0xffffu) + bv.z;
    float s3 = b2f(xv.y >> 16)     + bv.w;
#pragma unroll
    for (int c = 0; c < 4; c++) {
        uint2 p = *(const uint2*)(part + (size_t)c * 4194304 + i);
        s0 += b2f(p.x & 0xffffu);
        s1 += b2f(p.x >> 16);
        s2 += b2f(p.y & 0xffffu);
        s3 += b2f(p.y >> 16);
    }
    float4 r; r.x = s0; r.y = s1; r.z = s2; r.w = s3;
    *(float4*)(out + i) = r;
}

// ---------------------------------------------------------------------------
// Narrow-N GEMM variant: tile 128(M)x64(N), BK=64 -> grid (N/64)x(M/128).
// ---------------------------------------------------------------------------
template<int OBF, int BIAS, int RES, int RELU>
__global__ __launch_bounds__(256) void gemm_n64(
    const u16* __restrict__ A, const u16* __restrict__ Bt,
    const float* __restrict__ bias, const float* res,
    void* Cout, int M, int N, int K)
{
    __shared__ u16 As[2][8192];    // 128 x 64
    __shared__ u16 Bs[2][4096];    // 64 x 64
    const int tid = threadIdx.x;
    const int l = tid & 63, w = tid >> 6;
    const int wr = w >> 1, wc = w & 1;
    const int g = l >> 4, c16 = l & 15;
    const int m0 = blockIdx.y * 128, n0 = blockIdx.x * 64;

    const u16* a_src[4];
    int a_dst[4];
#pragma unroll
    for (int i = 0; i < 4; i++) {
        int G = tid + 256 * i, r = G >> 3, sl = G & 7;
        a_src[i] = A + (size_t)(m0 + r) * K + ((sl ^ (r & 7)) << 3);
        a_dst[i] = G * 8;
    }
    const u16* b_src[2];
    int b_dst[2];
#pragma unroll
    for (int i = 0; i < 2; i++) {
        int G = tid + 256 * i, r = G >> 3, sl = G & 7;
        b_src[i] = Bt + (size_t)(n0 + r) * K + ((sl ^ (r & 7)) << 3);
        b_dst[i] = G * 8;
    }

    f32x4 acc[4][2];
#pragma unroll
    for (int i = 0; i < 4; i++)
#pragma unroll
        for (int j = 0; j < 2; j++) acc[i][j] = (f32x4){0.f, 0.f, 0.f, 0.f};

#define STAGE_N64(nb, k0) do {                                   \
        GLL16(a_src[0] + (k0), &As[nb][a_dst[0]]);               \
        GLL16(a_src[1] + (k0), &As[nb][a_dst[1]]);               \
        GLL16(a_src[2] + (k0), &As[nb][a_dst[2]]);               \
        GLL16(a_src[3] + (k0), &As[nb][a_dst[3]]);               \
        GLL16(b_src[0] + (k0), &Bs[nb][b_dst[0]]);               \
        GLL16(b_src[1] + (k0), &Bs[nb][b_dst[1]]);               \
    } while (0)

    STAGE_N64(0, 0);
    __syncthreads();

    int cur = 0;
    for (int k0 = 0; k0 < K; k0 += 64) {
        if (k0 + 64 < K) STAGE_N64(cur ^ 1, k0 + 64);
        const u16* AsC = As[cur];
        const u16* BsC = Bs[cur];
        bf16x8 af[4][2], bfr[2][2];
#pragma unroll
        for (int fi = 0; fi < 4; fi++) {
            int r = wr * 64 + fi * 16 + c16;
            af[fi][0] = *(const bf16x8*)&AsC[r * 64 + (((g    ) ^ (r & 7)) << 3)];
            af[fi][1] = *(const bf16x8*)&AsC[r * 64 + (((4 + g) ^ (r & 7)) << 3)];
        }
#pragma unroll
        for (int fj = 0; fj < 2; fj++) {
            int r = wc * 32 + fj * 16 + c16;
            bfr[fj][0] = *(const bf16x8*)&BsC[r * 64 + (((g    ) ^ (r & 7)) << 3)];
            bfr[fj][1] = *(const bf16x8*)&BsC[r * 64 + (((4 + g) ^ (r & 7)) << 3)];
        }
#pragma unroll
        for (int fi = 0; fi < 4; fi++)
#pragma unroll
            for (int fj = 0; fj < 2; fj++) {
                acc[fi][fj] = MFMA16(af[fi][0], bfr[fj][0], acc[fi][fj]);
                acc[fi][fj] = MFMA16(af[fi][1], bfr[fj][1], acc[fi][fj]);
            }
        __syncthreads();
        cur ^= 1;
    }
#undef STAGE_N64

#pragma unroll
    for (int fi = 0; fi < 4; fi++)
#pragma unroll
        for (int fj = 0; fj < 2; fj++) {
            int coln = n0 + wc * 32 + fj * 16 + c16;
            float bv = BIAS ? bias[coln] : 0.f;
#pragma unroll
            for (int reg = 0; reg < 4; reg++) {
                int rowm = m0 + wr * 64 + fi * 16 + 4 * g + reg;
                float v = acc[fi][fj][reg] + bv;
                if (RES) v += res[(size_t)rowm * N + coln];
                if (RELU) v = fmaxf(v, 0.f);
                if (OBF) ((u16*)Cout)[(size_t)rowm * N + coln] = f2b(v);
                else     ((float*)Cout)[(size_t)rowm * N + coln] = v;
            }
        }
}

// ---------------------------------------------------------------------------
// qkv bf16 [4096][3072] (v at col 2048+h*64+d) -> vT bf16 [(b*16+h)*64+d][2048]
// ---------------------------------------------------------------------------
__global__ __launch_bounds__(256) void v_transpose(
    const u16* __restrict__ qkv, u16* __restrict__ vT)
{
    int t0 = blockIdx.x * 64, h = blockIdx.y, b = blockIdx.z;
    __shared__ u16 t[64][72];
    int tid = threadIdx.x;
#pragma unroll
    for (int it = 0; it < 2; it++) {
        int r = it * 32 + (tid >> 3);
        int cs = (tid & 7) * 8;
        *(uint4*)&t[r][cs] =
            *(const uint4*)(qkv + (size_t)(b * 2048 + t0 + r) * 3072 + 2048 + h * 64 + cs);
    }
    __syncthreads();
    int d = tid >> 2, seg = tid & 3;
    union { u16 u[8]; uint4 q; } pk;
#pragma unroll
    for (int hq = 0; hq < 2; hq++) {
#pragma unroll
        for (int j = 0; j < 8; j++) pk.u[j] = t[seg * 16 + hq * 8 + j][d];
        *(uint4*)(vT + (size_t)((b * 16 + h) * 64 + d) * 2048 + t0 + seg * 16 + hq * 8) = pk.q;
    }
}

// ---------------------------------------------------------------------------
// MFMA flash attention (causal, no 1/sqrt(d) scale — per reference).
// QBLK=128, 8 waves = (kg k-half) x (qg 32 q-rows); swapped QK^T; no-max
// softmax; counted-vmcnt double-buffered K/V; balanced qt mapping.
// ---------------------------------------------------------------------------
__global__ __launch_bounds__(512) void attn_mfma(
    const u16* __restrict__ qkv, const u16* __restrict__ vT,
    u16* __restrict__ outb)
{
    __shared__ u16 smem[24576];    // Ks 2x8KB | Vs 2x8KB | Ps 16KB = 48KB
    u16* KsB = smem;               // [2][4096]
    u16* VsB = smem + 8192;        // [2][4096]
    u16* PsB = smem + 16384;       // 128 q-rows x 64 k, stride 64 + XOR swz
    const int tid = threadIdx.x, l = tid & 63, w = tid >> 6;   // w 0..7
    const int g = l >> 4, c16 = l & 15;
    const int qg = w & 3, kg = w >> 2;            // q-group, k-half
    const int kg32 = kg * 32, kg64 = kg * 64;
    const int bh = blockIdx.y, b = bh >> 4, h = bh & 15;
    const int bx = (int)blockIdx.x;
    const int qt = (bh < 16) ? (15 - bx) : bx;    // balanced pair mapping
    const int r0 = qt * 128;
    const int wq0 = r0 + qg * 32;                 // wave's base q-row (32 rows)

    bf16x8 qf[2][2];
#pragma unroll
    for (int grp = 0; grp < 2; grp++) {
        const u16* qrow = qkv + (size_t)(b * 2048 + wq0 + grp * 16 + c16) * 3072 + h * 64;
        qf[grp][0] = *(const bf16x8*)(qrow + g * 8);
        qf[grp][1] = *(const bf16x8*)(qrow + 32 + g * 8);
    }

    const int kr = tid >> 3, ks = (tid & 7) ^ (kr & 7);
    const u16* kgp = qkv + (size_t)(b * 2048) * 3072 + 1024 + h * 64;
    const u16* vgp = vT + (size_t)((b * 16 + h) * 64) * 2048;

    float lrow[2] = {0.f, 0.f};
    f32x4 oacc[2][4];
#pragma unroll
    for (int grp = 0; grp < 2; grp++)
#pragma unroll
        for (int i = 0; i < 4; i++) oacc[grp][i] = (f32x4){0.f, 0.f, 0.f, 0.f};

    const int prow0 = (qg * 32 + c16) * 128;      // BYTE row base (grp0)
    const int swz   = (c16 & 7) << 4;             // 16B-chunk XOR (bytes)

#define STAGE_KV(nb, s0) do {                                                  \
        GLL16(kgp + (size_t)((s0) + kr) * 3072 + ks * 8, &KsB[(nb)*4096 + tid*8]); \
        GLL16(vgp + (size_t)kr * 2048 + (s0) + ks * 8, &VsB[(nb)*4096 + tid*8]);   \
    } while (0)

    STAGE_KV(0, 0);
    asm volatile("s_waitcnt vmcnt(0)" ::: "memory");
    __builtin_amdgcn_sched_barrier(0);
    __builtin_amdgcn_s_barrier();                 // buf0 certified for all

    const int nt = 2 * qt + 2;                    // 64-col K-tiles
    int cur = 0;
    for (int kt = 0; kt < nt; kt++) {
        if (kt + 1 < nt) STAGE_KV(cur ^ 1, (kt + 1) * 64);
        if (kt > 0) {
            if (kt + 1 < nt) asm volatile("s_waitcnt vmcnt(2)" ::: "memory");
            else             asm volatile("s_waitcnt vmcnt(0)" ::: "memory");
            __builtin_amdgcn_sched_barrier(0);
            __builtin_amdgcn_s_barrier();
        }
        const u16* KsC = &KsB[cur * 4096];
        const u16* VsC = &VsB[cur * 4096];
        const int s0 = kt * 64;

        bf16x8 kf0[2], kf1[2];
#pragma unroll
        for (int fj = 0; fj < 2; fj++) {
            int r = kg32 + fj * 16 + c16;
            kf0[fj] = *(const bf16x8*)&KsC[r * 64 + ((g       ^ (r & 7)) << 3)];
            kf1[fj] = *(const bf16x8*)&KsC[r * 64 + (((4 + g) ^ (r & 7)) << 3)];
        }
#pragma unroll
        for (int grp = 0; grp < 2; grp++) {
            f32x4 sc[2];
            sc[0] = (f32x4){0.f, 0.f, 0.f, 0.f};
            sc[1] = (f32x4){0.f, 0.f, 0.f, 0.f};
#pragma unroll
            for (int fj = 0; fj < 2; fj++) {
                sc[fj] = MFMA16(kf0[fj], qf[grp][0], sc[fj]);   // SWAPPED: S^T
                sc[fj] = MFMA16(kf1[fj], qf[grp][1], sc[fj]);
            }
            const int qgl = wq0 + grp * 16 + c16;  // this lane's q row
            if (s0 + kg32 + 31 > wq0 + grp * 16) { // causal frontier possible
#pragma unroll
                for (int fj = 0; fj < 2; fj++)
#pragma unroll
                    for (int reg = 0; reg < 4; reg++)
                        if (s0 + kg32 + fj * 16 + 4 * g + reg > qgl)
                            sc[fj][reg] = -1e30f;
            }
#pragma unroll
            for (int fj = 0; fj < 2; fj++) {
                float p0 = __expf(sc[fj][0]);
                float p1 = __expf(sc[fj][1]);
                float p2 = __expf(sc[fj][2]);
                float p3 = __expf(sc[fj][3]);
                lrow[grp] += (p0 + p1) + (p2 + p3);
                uint2 pk;
                pk.x = cvtpk(p0, p1);
                pk.y = cvtpk(p2, p3);
                *(uint2*)((char*)PsB + prow0 + grp * 2048 +
                          ((kg64 + fj * 32 + 8 * g) ^ swz)) = pk;
            }
        }
        bf16x8 pa0 = *(const bf16x8*)((const char*)PsB + prow0 +
                                      ((kg64 + 16 * g) ^ swz));
        bf16x8 pa1 = *(const bf16x8*)((const char*)PsB + prow0 + 2048 +
                                      ((kg64 + 16 * g) ^ swz));
#pragma unroll
        for (int fd = 0; fd < 4; fd++) {
            int r = fd * 16 + c16;
            bf16x8 vf = *(const bf16x8*)&VsC[r * 64 + (((4 * kg + g) ^ (r & 7)) << 3)];
            oacc[0][fd] = MFMA16(pa0, vf, oacc[0][fd]);
            oacc[1][fd] = MFMA16(pa1, vf, oacc[1][fd]);
        }
        __builtin_amdgcn_s_barrier();
        cur ^= 1;
    }
#undef STAGE_KV

#pragma unroll
    for (int grp = 0; grp < 2; grp++) {
        lrow[grp] += __shfl_xor(lrow[grp], 16);
        lrow[grp] += __shfl_xor(lrow[grp], 32);
    }

    __syncthreads();
    float* scr = (float*)smem;                     // 48KB >= 4*64*36*4B
    const int sbase = qg * 2304 + l * 36;          // 16B-aligned per lane
    if (kg == 1) {
#pragma unroll
        for (int grp = 0; grp < 2; grp++) {
#pragma unroll
            for (int fd = 0; fd < 4; fd++)
                *(f32x4*)&scr[sbase + grp * 16 + fd * 4] = oacc[grp][fd];
            scr[sbase + 32 + grp] = lrow[grp];
        }
    }
    __syncthreads();
    if (kg == 0) {
#pragma unroll
        for (int grp = 0; grp < 2; grp++) {
#pragma unroll
            for (int fd = 0; fd < 4; fd++)
                oacc[grp][fd] += *(const f32x4*)&scr[sbase + grp * 16 + fd * 4];
            float lr = lrow[grp] + scr[sbase + 32 + grp];
#pragma unroll
            for (int reg = 0; reg < 4; reg++) {
                float ls = __shfl(lr, 4 * g + reg);   // lsum of q-row 4g+reg
                float inv = 1.0f / ls;
                int t = wq0 + grp * 16 + 4 * g + reg;
                u16* op = outb + (size_t)(b * 2048 + t) * 1024 + h * 64;
#pragma unroll
                for (int fd = 0; fd < 4; fd++)
                    op[fd * 16 + c16] = f2b(oacc[grp][fd][reg] * inv);
            }
        }
    }
}

// ---------------------------------------------------------------------------
extern "C" void kernel_launch(void* const* d_in, const int* in_sizes, int n_in,
                              void* d_out, int out_size, void* d_ws, size_t ws_size,
                              hipStream_t stream) {
    const float* x     = (const float*)d_in[0];
    const float* ln1w  = (const float*)d_in[1];
    const float* ln1b  = (const float*)d_in[2];
    const float* Wq    = (const float*)d_in[3];
    const float* Wk    = (const float*)d_in[4];
    const float* Wv    = (const float*)d_in[5];
    const float* projw = (const float*)d_in[6];
    const float* projb = (const float*)d_in[7];
    const float* ln2w  = (const float*)d_in[8];
    const float* ln2b  = (const float*)d_in[9];
    const float* fc1w  = (const float*)d_in[10];
    const float* fc1b  = (const float*)d_in[11];
    const float* fc2w  = (const float*)d_in[12];
    const float* fc2b  = (const float*)d_in[13];
    float* out = (float*)d_out;

    u16* h_bf    = (u16*)d_ws;                 // 4096*1024
    u16* qkv_bf  = h_bf    + 4194304;          // 4096*3072
    u16* vTb     = qkv_bf  + 12582912;         // 2048*2048
    u16* attn_bf = vTb     + 4194304;          // 4096*1024
    u16* ff1_bf  = attn_bf + 4194304;          // 4096*4096
    u16* WtQKV   = ff1_bf  + 16777216;         // 3072*1024
    u16* WtP     = WtQKV   + 3145728;          // 1024*1024
    u16* Wt1     = WtP     + 1048576;          // 4096*1024
    u16* Wt2     = Wt1     + 4194304;          // 1024*4096
    u16* x1_bf   = Wt2     + 4194304;          // 4096*1024 (x + sa, bf16)
    // FC2 split-K bf16 partials (4 x 4096x1024 u16 = 32MB) reuse the
    // h_bf..qkv_bf region (dead by FC2 time; rewritten every launch).
    u16* fc2p = (u16*)d_ws;

    repack_all<<<dim3(3072), 256, 0, stream>>>(
        Wq, Wk, Wv, WtQKV, projw, WtP, fc1w, Wt1, fc2w, Wt2);

    ln_bf16<<<1024, 256, 0, stream>>>(x, ln1w, ln1b, h_bf);
    gemm_qkv<<<dim3(256), 512, 0, stream>>>(h_bf, WtQKV, qkv_bf);
    v_transpose<<<dim3(32, 16, 2), 256, 0, stream>>>(qkv_bf, vTb);
    attn_mfma<<<dim3(16, 32), 512, 0, stream>>>(qkv_bf, vTb, attn_bf);
    gemm_n64<1, 1, 1, 0><<<dim3(16, 32), 256, 0, stream>>>(
        attn_bf, WtP, projb, x, x1_bf, Mn, 1024, 1024);
    ln_bf16_b<<<1024, 256, 0, stream>>>(x1_bf, ln2w, ln2b, h_bf);
    gemm_8ph<1, 1, 1><<<dim3(256), 512, 0, stream>>>(
        h_bf, Wt1, fc1b, ff1_bf, Mn, 4096, 1024, 16);
    gemm_fc2<<<dim3(256), 512, 0, stream>>>(ff1_bf, Wt2, fc2p);
    splitk_reduce<<<dim3(4096), 256, 0, stream>>>(fc2p, x1_bf, fc2b, out);
}

// Round 19
// 193.658 us; speedup vs baseline: 1.0491x; 1.0263x over previous
//
#include <hip/hip_runtime.h>
#include <hip/hip_bf16.h>

#define Bn 2
#define Tn 2048
#define Cn 1024
#define Hn 16
#define HSn 64
#define Mn (Bn*Tn)          // 4096
#define LN_EPS 1e-5f

typedef unsigned short u16;
typedef __attribute__((ext_vector_type(8))) short bf16x8;   // 8 bf16 = 4 VGPRs
typedef __attribute__((ext_vector_type(4))) float f32x4;

#define MFMA16(a,b,c) __builtin_amdgcn_mfma_f32_16x16x32_bf16(a, b, c, 0, 0, 0)
#define GLL16(g,l) __builtin_amdgcn_global_load_lds( \
    (const __attribute__((address_space(1))) void*)(g), \
    (__attribute__((address_space(3))) void*)(l), 16, 0, 0)

__device__ __forceinline__ u16 f2b(float f) {               // f32 -> bf16 RNE
    unsigned int u = __float_as_uint(f);
    unsigned int r = (u + 0x7FFFu + ((u >> 16) & 1u)) >> 16;
    return (u16)r;
}
__device__ __forceinline__ float b2f(unsigned u) {          // bf16 -> f32
    return __uint_as_float(u << 16);
}
__device__ __forceinline__ unsigned cvtpk(float lo, float hi) { // [hi|lo] bf16x2
    unsigned r;
    asm("v_cvt_pk_bf16_f32 %0, %1, %2" : "=v"(r) : "v"(lo), "v"(hi));
    return r;
}

// ---------------------------------------------------------------------------
// Shared 64x64 transpose-convert tile body (f32 in -> bf16 out^T).
// ---------------------------------------------------------------------------
__device__ __forceinline__ void trans_tile(
    const float* __restrict__ in, u16* __restrict__ out,
    int R, int C, int r0, int c0c, float (*t)[68], int tid)
{
#pragma unroll
    for (int it = 0; it < 4; it++) {
        int r = it * 16 + (tid >> 4);
        *(float4*)&t[r][(tid & 15) * 4] =
            *(const float4*)(in + (size_t)(r0 + r) * C + c0c + (tid & 15) * 4);
    }
    __syncthreads();
    int c = tid >> 2, seg = tid & 3;
    union { u16 u[8]; uint4 q; } pk;
#pragma unroll
    for (int hq = 0; hq < 2; hq++) {
#pragma unroll
        for (int j = 0; j < 8; j++) pk.u[j] = f2b(t[seg * 16 + hq * 8 + j][c]);
        *(uint4*)(out + (size_t)(c0c + c) * R + r0 + seg * 16 + hq * 8) = pk.q;
    }
}

// ---------------------------------------------------------------------------
// Fused prologue: all four weight transposes + LN1 in ONE launch (4096 blocks).
// [0,768): Wq/Wk/Wv [H][C][64] -> WtQKV^T [3072][1024]
// [768,1024): projw 1024x1024 -> WtP^T
// [1024,2048): fc1w 1024x4096 -> Wt1^T [4096][1024]
// [2048,3072): fc2w 4096x1024 -> Wt2^T [1024][4096]
// [3072,4096): LayerNorm1 (f32 x -> bf16 h), 4 rows/block (1 wave each)
// All paths read only d_in and write disjoint d_ws regions.
// ---------------------------------------------------------------------------
__global__ __launch_bounds__(256) void repack_all(
    const float* __restrict__ Wq, const float* __restrict__ Wk,
    const float* __restrict__ Wv, u16* __restrict__ WtQKV,
    const float* __restrict__ projw, u16* __restrict__ WtP,
    const float* __restrict__ fc1w, u16* __restrict__ Wt1,
    const float* __restrict__ fc2w, u16* __restrict__ Wt2,
    const float* __restrict__ x, const float* __restrict__ ln1w,
    const float* __restrict__ ln1b, u16* __restrict__ h_out)
{
    __shared__ float t[64][68];
    const int bid = (int)blockIdx.x, tid = threadIdx.x;
    if (bid < 768) {
        int z = bid >> 8, rem = bid & 255, h = rem >> 4, c0 = (rem & 15) * 64;
        const float* in = (z == 0 ? Wq : z == 1 ? Wk : Wv) + (size_t)h * 65536;
        u16* outb = WtQKV + (size_t)(z * 1024 + h * 64) * 1024;
        trans_tile(in, outb, 1024, 64, c0, 0, t, tid);
    } else if (bid < 1024) {
        int idx = bid - 768, bx = idx & 15, by = idx >> 4;
        trans_tile(projw, WtP, 1024, 1024, by * 64, bx * 64, t, tid);
    } else if (bid < 2048) {
        int idx = bid - 1024, bx = idx & 63, by = idx >> 6;
        trans_tile(fc1w, Wt1, 1024, 4096, by * 64, bx * 64, t, tid);
    } else if (bid < 3072) {
        int idx = bid - 2048, bx = idx & 15, by = idx >> 4;
        trans_tile(fc2w, Wt2, 4096, 1024, by * 64, bx * 64, t, tid);
    } else {
        // LayerNorm1: row = (bid-3072)*4 + wave; one wave per row
        int row  = (bid - 3072) * 4 + (tid >> 6);
        int lane = tid & 63;
        const float* xr = x + (size_t)row * Cn;
        float4 v[4];
        float s = 0.f, sq = 0.f;
#pragma unroll
        for (int i = 0; i < 4; i++) {
            v[i] = *(const float4*)(xr + lane * 4 + i * 256);
            s  += v[i].x + v[i].y + v[i].z + v[i].w;
            sq += v[i].x * v[i].x + v[i].y * v[i].y + v[i].z * v[i].z + v[i].w * v[i].w;
        }
#pragma unroll
        for (int off = 1; off < 64; off <<= 1) {
            s  += __shfl_xor(s, off);
            sq += __shfl_xor(sq, off);
        }
        float mu   = s * (1.f / Cn);
        float var  = sq * (1.f / Cn) - mu * mu;
        float rstd = rsqrtf(var + LN_EPS);
        u16* orow = h_out + (size_t)row * Cn;
#pragma unroll
        for (int i = 0; i < 4; i++) {
            float4 w4 = *(const float4*)(ln1w + lane * 4 + i * 256);
            float4 b4 = *(const float4*)(ln1b + lane * 4 + i * 256);
            union { u16 u[4]; uint2 q; } pk;
            pk.u[0] = f2b((v[i].x - mu) * rstd * w4.x + b4.x);
            pk.u[1] = f2b((v[i].y - mu) * rstd * w4.y + b4.y);
            pk.u[2] = f2b((v[i].z - mu) * rstd * w4.z + b4.z);
            pk.u[3] = f2b((v[i].w - mu) * rstd * w4.w + b4.w);
            *(uint2*)(orow + lane * 4 + i * 256) = pk.q;
        }
    }
}

// ---------------------------------------------------------------------------
// LayerNorm bf16 in -> bf16 out. One wave per row (16 elems/lane, contiguous).
// ---------------------------------------------------------------------------
__global__ __launch_bounds__(256) void ln_bf16_b(
    const u16* __restrict__ x, const float* __restrict__ w,
    const float* __restrict__ bvec, u16* __restrict__ out)
{
    int row  = blockIdx.x * 4 + (threadIdx.x >> 6);
    int lane = threadIdx.x & 63;
    const u16* xr = x + (size_t)row * Cn + lane * 16;
    float v[16];
    float s = 0.f, sq = 0.f;
#pragma unroll
    for (int i = 0; i < 2; i++) {
        uint4 q = *(const uint4*)(xr + i * 8);
        float* vv = v + i * 8;
        vv[0] = b2f(q.x & 0xffffu); vv[1] = b2f(q.x >> 16);
        vv[2] = b2f(q.y & 0xffffu); vv[3] = b2f(q.y >> 16);
        vv[4] = b2f(q.z & 0xffffu); vv[5] = b2f(q.z >> 16);
        vv[6] = b2f(q.w & 0xffffu); vv[7] = b2f(q.w >> 16);
    }
#pragma unroll
    for (int j = 0; j < 16; j++) { s += v[j]; sq += v[j] * v[j]; }
#pragma unroll
    for (int off = 1; off < 64; off <<= 1) {
        s  += __shfl_xor(s, off);
        sq += __shfl_xor(sq, off);
    }
    float mu   = s * (1.f / Cn);
    float var  = sq * (1.f / Cn) - mu * mu;
    float rstd = rsqrtf(var + LN_EPS);
    u16* orow = out + (size_t)row * Cn + lane * 16;
#pragma unroll
    for (int i = 0; i < 2; i++) {
        union { u16 u[8]; uint4 q; } pk;
#pragma unroll
        for (int j = 0; j < 8; j++) {
            int col = lane * 16 + i * 8 + j;
            pk.u[j] = f2b((v[i * 8 + j] - mu) * rstd * w[col] + bvec[col]);
        }
        *(uint4*)(orow + i * 8) = pk.q;
    }
}

// ---------------------------------------------------------------------------
// 8-phase 256x256 MFMA GEMM (T2+T3+T4+T5 port, plain HIP). Used for FC1.
// ---------------------------------------------------------------------------
template<int OBF, int BIAS, int RELU>
__global__ __launch_bounds__(512, 2) void gemm_8ph(
    const u16* __restrict__ A, const u16* __restrict__ Bt,
    const float* __restrict__ bias, void* Cout,
    int M, int N, int K, int NT)
{
    __shared__ u16 lds[65536];                 // 128 KiB
    const int tid = threadIdx.x, l = tid & 63, w = tid >> 6;
    const int wm = w >> 2, wn = w & 3;
    const int g = l >> 4, c16 = l & 15;

    const int nwg = (int)gridDim.x, cpx = nwg >> 3;
    const int bid = (int)blockIdx.x;
    const int sbid = (bid & 7) * cpx + (bid >> 3);
    const int m0 = (sbid / NT) * 256, n0 = (sbid % NT) * 256;

    const int sr = tid >> 3;
    const int ss = ((tid & 7) ^ (sr & 7)) << 3;
    const u16* Asrc = A  + (size_t)(m0 + sr) * K + ss;
    const u16* Bsrc = Bt + (size_t)(n0 + sr) * K + ss;
    const int dst0 = tid * 8;

#define ST_A8(d_, h_, kt_) do {                                              \
        GLL16(Asrc + (size_t)((h_) * 128) * K + (size_t)(kt_) * 64,          \
              &lds[(d_) * 32768 + (h_) * 8192 + dst0]);                      \
        GLL16(Asrc + (size_t)((h_) * 128 + 64) * K + (size_t)(kt_) * 64,     \
              &lds[(d_) * 32768 + (h_) * 8192 + 4096 + dst0]);               \
    } while (0)
#define ST_B8(d_, h_, kt_) do {                                              \
        GLL16(Bsrc + (size_t)((h_) * 128) * K + (size_t)(kt_) * 64,          \
              &lds[(d_) * 32768 + 16384 + (h_) * 8192 + dst0]);              \
        GLL16(Bsrc + (size_t)((h_) * 128 + 64) * K + (size_t)(kt_) * 64,     \
              &lds[(d_) * 32768 + 16384 + (h_) * 8192 + 4096 + dst0]);       \
    } while (0)
#define LDA8(d_, mi_, s_) (*(const bf16x8*)&lds[(d_) * 32768 +               \
        (wm * 128 + (mi_) * 16 + c16) * 64 +                                  \
        ((((s_) * 4 + g) ^ ((wm * 128 + (mi_) * 16 + c16) & 7)) << 3)])
#define LDB8(d_, nj_, s_) (*(const bf16x8*)&lds[(d_) * 32768 + 16384 +       \
        (wn * 64 + (nj_) * 16 + c16) * 64 +                                   \
        ((((s_) * 4 + g) ^ ((wn * 64 + (nj_) * 16 + c16) & 7)) << 3)])
#define PH_HEAD() do {                                                       \
        __builtin_amdgcn_s_barrier();                                        \
        asm volatile("s_waitcnt lgkmcnt(0)" ::: "memory");                   \
        __builtin_amdgcn_sched_barrier(0);                                   \
        __builtin_amdgcn_s_setprio(1);                                       \
    } while (0)
#define PH_MFMA(NH_) do {                                                    \
        _Pragma("unroll")                                                    \
        for (int mi = 0; mi < 8; mi++) {                                     \
            acc[mi][2*(NH_)]   = MFMA16(aF[mi], bF[0], acc[mi][2*(NH_)]);    \
            acc[mi][2*(NH_)+1] = MFMA16(aF[mi], bF[1], acc[mi][2*(NH_)+1]);  \
        }                                                                    \
    } while (0)

    f32x4 acc[8][4];
#pragma unroll
    for (int i = 0; i < 8; i++)
#pragma unroll
        for (int j = 0; j < 4; j++) acc[i][j] = (f32x4){0.f, 0.f, 0.f, 0.f};

    const int nk = K >> 6;
    ST_A8(0, 0, 0); ST_A8(0, 1, 0); ST_B8(0, 0, 0); ST_B8(0, 1, 0);
    ST_A8(1, 0, 1); ST_A8(1, 1, 1);
    asm volatile("s_waitcnt vmcnt(4)" ::: "memory");
    __builtin_amdgcn_s_barrier();

    bf16x8 aF[8], bF[2];
    for (int m = 0; m < nk; m++) {
        const int d = m & 1, dn = d ^ 1;
#pragma unroll
        for (int mi = 0; mi < 8; mi++) aF[mi] = LDA8(d, mi, 0);
        bF[0] = LDB8(d, 0, 0); bF[1] = LDB8(d, 1, 0);
        if (m + 1 < nk) ST_B8(dn, 0, m + 1);
        PH_HEAD(); PH_MFMA(0);
        __builtin_amdgcn_s_setprio(0);
        __builtin_amdgcn_s_barrier();
        bF[0] = LDB8(d, 2, 0); bF[1] = LDB8(d, 3, 0);
        if (m + 1 < nk) ST_B8(dn, 1, m + 1);
        PH_HEAD(); PH_MFMA(1);
        __builtin_amdgcn_s_setprio(0);
        __builtin_amdgcn_s_barrier();
#pragma unroll
        for (int mi = 0; mi < 8; mi++) aF[mi] = LDA8(d, mi, 1);
        bF[0] = LDB8(d, 0, 1); bF[1] = LDB8(d, 1, 1);
        PH_HEAD(); PH_MFMA(0);
        __builtin_amdgcn_s_setprio(0);
        __builtin_amdgcn_s_barrier();
        bF[0] = LDB8(d, 2, 1); bF[1] = LDB8(d, 3, 1);
        if (m + 2 < nk) { ST_A8(d, 0, m + 2); ST_A8(d, 1, m + 2); }
        PH_HEAD(); PH_MFMA(1);
        __builtin_amdgcn_s_setprio(0);
        if (m + 1 < nk) {
            if (m + 2 < nk) asm volatile("s_waitcnt vmcnt(4)" ::: "memory");
            else            asm volatile("s_waitcnt vmcnt(0)" ::: "memory");
        }
        __builtin_amdgcn_s_barrier();
    }
#undef ST_A8
#undef ST_B8
#undef LDA8
#undef LDB8
#undef PH_HEAD
#undef PH_MFMA

#pragma unroll
    for (int mi = 0; mi < 8; mi++)
#pragma unroll
        for (int nj = 0; nj < 4; nj++) {
            const int coln = n0 + wn * 64 + nj * 16 + c16;
            float bv = BIAS ? bias[coln] : 0.f;
#pragma unroll
            for (int reg = 0; reg < 4; reg++) {
                int rowm = m0 + wm * 128 + mi * 16 + 4 * g + reg;
                float v = acc[mi][nj][reg] + bv;
                if (RELU) v = fmaxf(v, 0.f);
                if (OBF) ((u16*)Cout)[(size_t)rowm * N + coln] = f2b(v);
                else     ((float*)Cout)[(size_t)rowm * N + coln] = v;
            }
        }
}

// ---------------------------------------------------------------------------
// QKV 8-phase GEMM, tile 256(M) x 192(N), BK=64: grid 16x16 = 256 blocks.
// ---------------------------------------------------------------------------
__global__ __launch_bounds__(512, 1) void gemm_qkv(
    const u16* __restrict__ A, const u16* __restrict__ Bt,
    u16* __restrict__ Cout)
{
    __shared__ u16 lds[57344];                 // A 2x32KB | B 2x24KB = 112 KiB
    const int tid = threadIdx.x, l = tid & 63, w = tid >> 6;
    const int wm = w >> 1, wn = w & 1;         // 4M x 2N waves
    const int g = l >> 4, c16 = l & 15;
    const int K = 1024, N = 3072;

    const int bid = (int)blockIdx.x;
    const int sbid = (bid & 7) * 32 + (bid >> 3);      // grid 256, bijective
    const int m0 = (sbid >> 4) * 256, n0 = (sbid & 15) * 192;

    const int sr = tid >> 3;
    const int ss = ((tid & 7) ^ (sr & 7)) << 3;
    const u16* Asrc = A  + (size_t)(m0 + sr) * K + ss;
    const u16* Bsrc = Bt + (size_t)(n0 + sr) * K + ss;
    const int dst0 = tid * 8;

#define ST_A(d_, h_, kt_) do {                                               \
        GLL16(Asrc + (size_t)((h_) * 128) * K + (size_t)(kt_) * 64,          \
              &lds[(d_) * 16384 + (h_) * 8192 + dst0]);                      \
        GLL16(Asrc + (size_t)((h_) * 128 + 64) * K + (size_t)(kt_) * 64,     \
              &lds[(d_) * 16384 + (h_) * 8192 + 4096 + dst0]);               \
    } while (0)
#define ST_B1(d_, seg_, kt_)                                                 \
        GLL16(Bsrc + (size_t)((seg_) * 64) * K + (size_t)(kt_) * 64,         \
              &lds[32768 + (d_) * 12288 + (seg_) * 4096 + dst0])
#define LDA(d_, mi_, s_) (*(const bf16x8*)&lds[(d_) * 16384 +                \
        (wm * 64 + (mi_) * 16 + c16) * 64 +                                   \
        ((((s_) * 4 + g) ^ ((wm * 64 + (mi_) * 16 + c16) & 7)) << 3)])
#define LDB(d_, nj_, s_) (*(const bf16x8*)&lds[32768 + (d_) * 12288 +        \
        (wn * 96 + (nj_) * 16 + c16) * 64 +                                   \
        ((((s_) * 4 + g) ^ ((wn * 96 + (nj_) * 16 + c16) & 7)) << 3)])
#define PH_HEAD() do {                                                       \
        __builtin_amdgcn_s_barrier();                                        \
        asm volatile("s_waitcnt lgkmcnt(0)" ::: "memory");                   \
        __builtin_amdgcn_sched_barrier(0);                                   \
        __builtin_amdgcn_s_setprio(1);                                       \
    } while (0)
#define PH_MFMA(NH_) do {                                                    \
        _Pragma("unroll")                                                    \
        for (int mi = 0; mi < 4; mi++) {                                     \
            acc[mi][3*(NH_)]   = MFMA16(aF[mi], bF[0], acc[mi][3*(NH_)]);    \
            acc[mi][3*(NH_)+1] = MFMA16(aF[mi], bF[1], acc[mi][3*(NH_)+1]);  \
            acc[mi][3*(NH_)+2] = MFMA16(aF[mi], bF[2], acc[mi][3*(NH_)+2]);  \
        }                                                                    \
    } while (0)

    f32x4 acc[4][6];
#pragma unroll
    for (int i = 0; i < 4; i++)
#pragma unroll
        for (int j = 0; j < 6; j++) acc[i][j] = (f32x4){0.f, 0.f, 0.f, 0.f};

    const int nk = 16;
    ST_A(0, 0, 0); ST_A(0, 1, 0);
    ST_B1(0, 0, 0); ST_B1(0, 1, 0); ST_B1(0, 2, 0);
    ST_A(1, 0, 1); ST_A(1, 1, 1);
    asm volatile("s_waitcnt vmcnt(4)" ::: "memory");
    __builtin_amdgcn_s_barrier();

    bf16x8 aF[4], bF[3];
    for (int m = 0; m < nk; m++) {
        const int d = m & 1, dn = d ^ 1;
#pragma unroll
        for (int mi = 0; mi < 4; mi++) aF[mi] = LDA(d, mi, 0);
        bF[0] = LDB(d, 0, 0); bF[1] = LDB(d, 1, 0); bF[2] = LDB(d, 2, 0);
        if (m + 1 < nk) { ST_B1(dn, 0, m + 1); ST_B1(dn, 1, m + 1); }
        PH_HEAD(); PH_MFMA(0);
        __builtin_amdgcn_s_setprio(0);
        __builtin_amdgcn_s_barrier();
        bF[0] = LDB(d, 3, 0); bF[1] = LDB(d, 4, 0); bF[2] = LDB(d, 5, 0);
        if (m + 1 < nk) ST_B1(dn, 2, m + 1);
        PH_HEAD(); PH_MFMA(1);
        __builtin_amdgcn_s_setprio(0);
        __builtin_amdgcn_s_barrier();
#pragma unroll
        for (int mi = 0; mi < 4; mi++) aF[mi] = LDA(d, mi, 1);
        bF[0] = LDB(d, 0, 1); bF[1] = LDB(d, 1, 1); bF[2] = LDB(d, 2, 1);
        PH_HEAD(); PH_MFMA(0);
        __builtin_amdgcn_s_setprio(0);
        __builtin_amdgcn_s_barrier();
        bF[0] = LDB(d, 3, 1); bF[1] = LDB(d, 4, 1); bF[2] = LDB(d, 5, 1);
        if (m + 2 < nk) { ST_A(d, 0, m + 2); ST_A(d, 1, m + 2); }
        PH_HEAD(); PH_MFMA(1);
        __builtin_amdgcn_s_setprio(0);
        if (m + 1 < nk) {
            if (m + 2 < nk) asm volatile("s_waitcnt vmcnt(4)" ::: "memory");
            else            asm volatile("s_waitcnt vmcnt(0)" ::: "memory");
        }
        __builtin_amdgcn_s_barrier();
    }
#undef ST_A
#undef ST_B1
#undef LDA
#undef LDB
#undef PH_HEAD
#undef PH_MFMA

#pragma unroll
    for (int mi = 0; mi < 4; mi++)
#pragma unroll
        for (int nj = 0; nj < 6; nj++) {
            const int coln = n0 + wn * 96 + nj * 16 + c16;
#pragma unroll
            for (int reg = 0; reg < 4; reg++) {
                int rowm = m0 + wm * 64 + mi * 16 + 4 * g + reg;
                Cout[(size_t)rowm * N + coln] = f2b(acc[mi][nj][reg]);
            }
        }
}

// ---------------------------------------------------------------------------
// FC2 split-K 8-phase GEMM: bf16 partials; bias/residual in splitk_reduce.
// ---------------------------------------------------------------------------
__global__ __launch_bounds__(512, 2) void gemm_fc2(
    const u16* __restrict__ A, const u16* __restrict__ Bt,
    u16* __restrict__ part)
{
    __shared__ u16 lds[65536];
    const int tid = threadIdx.x, l = tid & 63, w = tid >> 6;
    const int wm = w >> 2, wn = w & 3;
    const int g = l >> 4, c16 = l & 15;

    const int bid = (int)blockIdx.x;
    const int sbid = (bid & 7) * 32 + (bid >> 3);     // grid 256, bijective
    const int chunk = sbid >> 6, t = sbid & 63;
    const int m0 = (t >> 2) * 256, n0 = (t & 3) * 256;
    const int kB = chunk << 10;

    const int sr = tid >> 3;
    const int ss = ((tid & 7) ^ (sr & 7)) << 3;
    const u16* Asrc = A  + (size_t)(m0 + sr) * 4096 + kB + ss;
    const u16* Bsrc = Bt + (size_t)(n0 + sr) * 4096 + kB + ss;
    const int dst0 = tid * 8;

#define ST_A8(d_, h_, kt_) do {                                              \
        GLL16(Asrc + (size_t)((h_) * 128) * 4096 + (size_t)(kt_) * 64,       \
              &lds[(d_) * 32768 + (h_) * 8192 + dst0]);                      \
        GLL16(Asrc + (size_t)((h_) * 128 + 64) * 4096 + (size_t)(kt_) * 64,  \
              &lds[(d_) * 32768 + (h_) * 8192 + 4096 + dst0]);               \
    } while (0)
#define ST_B8(d_, h_, kt_) do {                                              \
        GLL16(Bsrc + (size_t)((h_) * 128) * 4096 + (size_t)(kt_) * 64,       \
              &lds[(d_) * 32768 + 16384 + (h_) * 8192 + dst0]);              \
        GLL16(Bsrc + (size_t)((h_) * 128 + 64) * 4096 + (size_t)(kt_) * 64,  \
              &lds[(d_) * 32768 + 16384 + (h_) * 8192 + 4096 + dst0]);       \
    } while (0)
#define LDA8(d_, mi_, s_) (*(const bf16x8*)&lds[(d_) * 32768 +               \
        (wm * 128 + (mi_) * 16 + c16) * 64 +                                  \
        ((((s_) * 4 + g) ^ ((wm * 128 + (mi_) * 16 + c16) & 7)) << 3)])
#define LDB8(d_, nj_, s_) (*(const bf16x8*)&lds[(d_) * 32768 + 16384 +       \
        (wn * 64 + (nj_) * 16 + c16) * 64 +                                   \
        ((((s_) * 4 + g) ^ ((wn * 64 + (nj_) * 16 + c16) & 7)) << 3)])
#define PH_HEAD() do {                                                       \
        __builtin_amdgcn_s_barrier();                                        \
        asm volatile("s_waitcnt lgkmcnt(0)" ::: "memory");                   \
        __builtin_amdgcn_sched_barrier(0);                                   \
        __builtin_amdgcn_s_setprio(1);                                       \
    } while (0)
#define PH_MFMA(NH_) do {                                                    \
        _Pragma("unroll")                                                    \
        for (int mi = 0; mi < 8; mi++) {                                     \
            acc[mi][2*(NH_)]   = MFMA16(aF[mi], bF[0], acc[mi][2*(NH_)]);    \
            acc[mi][2*(NH_)+1] = MFMA16(aF[mi], bF[1], acc[mi][2*(NH_)+1]);  \
        }                                                                    \
    } while (0)

    f32x4 acc[8][4];
#pragma unroll
    for (int i = 0; i < 8; i++)
#pragma unroll
        for (int j = 0; j < 4; j++) acc[i][j] = (f32x4){0.f, 0.f, 0.f, 0.f};

    const int nk = 16;
    ST_A8(0, 0, 0); ST_A8(0, 1, 0); ST_B8(0, 0, 0); ST_B8(0, 1, 0);
    ST_A8(1, 0, 1); ST_A8(1, 1, 1);
    asm volatile("s_waitcnt vmcnt(4)" ::: "memory");
    __builtin_amdgcn_s_barrier();

    bf16x8 aF[8], bF[2];
    for (int m = 0; m < nk; m++) {
        const int d = m & 1, dn = d ^ 1;
#pragma unroll
        for (int mi = 0; mi < 8; mi++) aF[mi] = LDA8(d, mi, 0);
        bF[0] = LDB8(d, 0, 0); bF[1] = LDB8(d, 1, 0);
        if (m + 1 < nk) ST_B8(dn, 0, m + 1);
        PH_HEAD(); PH_MFMA(0);
        __builtin_amdgcn_s_setprio(0);
        __builtin_amdgcn_s_barrier();
        bF[0] = LDB8(d, 2, 0); bF[1] = LDB8(d, 3, 0);
        if (m + 1 < nk) ST_B8(dn, 1, m + 1);
        PH_HEAD(); PH_MFMA(1);
        __builtin_amdgcn_s_setprio(0);
        __builtin_amdgcn_s_barrier();
#pragma unroll
        for (int mi = 0; mi < 8; mi++) aF[mi] = LDA8(d, mi, 1);
        bF[0] = LDB8(d, 0, 1); bF[1] = LDB8(d, 1, 1);
        PH_HEAD(); PH_MFMA(0);
        __builtin_amdgcn_s_setprio(0);
        __builtin_amdgcn_s_barrier();
        bF[0] = LDB8(d, 2, 1); bF[1] = LDB8(d, 3, 1);
        if (m + 2 < nk) { ST_A8(d, 0, m + 2); ST_A8(d, 1, m + 2); }
        PH_HEAD(); PH_MFMA(1);
        __builtin_amdgcn_s_setprio(0);
        if (m + 1 < nk) {
            if (m + 2 < nk) asm volatile("s_waitcnt vmcnt(4)" ::: "memory");
            else            asm volatile("s_waitcnt vmcnt(0)" ::: "memory");
        }
        __builtin_amdgcn_s_barrier();
    }
#undef ST_A8
#undef ST_B8
#undef LDA8
#undef LDB8
#undef PH_HEAD
#undef PH_MFMA

    u16* pp = part + (size_t)chunk * 4194304;
#pragma unroll
    for (int mi = 0; mi < 8; mi++)
#pragma unroll
        for (int nj = 0; nj < 4; nj++) {
            const int coln = n0 + wn * 64 + nj * 16 + c16;
#pragma unroll
            for (int reg = 0; reg < 4; reg++) {
                int rowm = m0 + wm * 128 + mi * 16 + 4 * g + reg;
                pp[(size_t)rowm * 1024 + coln] = f2b(acc[mi][nj][reg]);
            }
        }
}

// ---------------------------------------------------------------------------
// splitk_reduce (fused): out[i] = x1_bf[i] + bias[col] + sum of 4 partials.
// Full overwrite of d_out (no RMW).
// ---------------------------------------------------------------------------
__global__ __launch_bounds__(256) void splitk_reduce(
    const u16* __restrict__ part, const u16* __restrict__ x1,
    const float* __restrict__ bias, float* __restrict__ out)
{
    size_t i = ((size_t)blockIdx.x * 256 + threadIdx.x) * 4;
    int col = (int)(i & 1023);
    float4 bv = *(const float4*)(bias + col);
    uint2 xv = *(const uint2*)(x1 + i);
    float s0 = b2f(xv.x & 0xffffu) + bv.x;
    float s1 = b2f(xv.x >> 16)     + bv.y;
    float s2 = b2f(xv.y & 0xffffu) + bv.z;
    float s3 = b2f(xv.y >> 16)     + bv.w;
#pragma unroll
    for (int c = 0; c < 4; c++) {
        uint2 p = *(const uint2*)(part + (size_t)c * 4194304 + i);
        s0 += b2f(p.x & 0xffffu);
        s1 += b2f(p.x >> 16);
        s2 += b2f(p.y & 0xffffu);
        s3 += b2f(p.y >> 16);
    }
    float4 r; r.x = s0; r.y = s1; r.z = s2; r.w = s3;
    *(float4*)(out + i) = r;
}

// ---------------------------------------------------------------------------
// Narrow-N GEMM variant: tile 128(M)x64(N), BK=64 -> grid (N/64)x(M/128).
// ---------------------------------------------------------------------------
template<int OBF, int BIAS, int RES, int RELU>
__global__ __launch_bounds__(256) void gemm_n64(
    const u16* __restrict__ A, const u16* __restrict__ Bt,
    const float* __restrict__ bias, const float* res,
    void* Cout, int M, int N, int K)
{
    __shared__ u16 As[2][8192];    // 128 x 64
    __shared__ u16 Bs[2][4096];    // 64 x 64
    const int tid = threadIdx.x;
    const int l = tid & 63, w = tid >> 6;
    const int wr = w >> 1, wc = w & 1;
    const int g = l >> 4, c16 = l & 15;
    const int m0 = blockIdx.y * 128, n0 = blockIdx.x * 64;

    const u16* a_src[4];
    int a_dst[4];
#pragma unroll
    for (int i = 0; i < 4; i++) {
        int G = tid + 256 * i, r = G >> 3, sl = G & 7;
        a_src[i] = A + (size_t)(m0 + r) * K + ((sl ^ (r & 7)) << 3);
        a_dst[i] = G * 8;
    }
    const u16* b_src[2];
    int b_dst[2];
#pragma unroll
    for (int i = 0; i < 2; i++) {
        int G = tid + 256 * i, r = G >> 3, sl = G & 7;
        b_src[i] = Bt + (size_t)(n0 + r) * K + ((sl ^ (r & 7)) << 3);
        b_dst[i] = G * 8;
    }

    f32x4 acc[4][2];
#pragma unroll
    for (int i = 0; i < 4; i++)
#pragma unroll
        for (int j = 0; j < 2; j++) acc[i][j] = (f32x4){0.f, 0.f, 0.f, 0.f};

#define STAGE_N64(nb, k0) do {                                   \
        GLL16(a_src[0] + (k0), &As[nb][a_dst[0]]);               \
        GLL16(a_src[1] + (k0), &As[nb][a_dst[1]]);               \
        GLL16(a_src[2] + (k0), &As[nb][a_dst[2]]);               \
        GLL16(a_src[3] + (k0), &As[nb][a_dst[3]]);               \
        GLL16(b_src[0] + (k0), &Bs[nb][b_dst[0]]);               \
        GLL16(b_src[1] + (k0), &Bs[nb][b_dst[1]]);               \
    } while (0)

    STAGE_N64(0, 0);
    __syncthreads();

    int cur = 0;
    for (int k0 = 0; k0 < K; k0 += 64) {
        if (k0 + 64 < K) STAGE_N64(cur ^ 1, k0 + 64);
        const u16* AsC = As[cur];
        const u16* BsC = Bs[cur];
        bf16x8 af[4][2], bfr[2][2];
#pragma unroll
        for (int fi = 0; fi < 4; fi++) {
            int r = wr * 64 + fi * 16 + c16;
            af[fi][0] = *(const bf16x8*)&AsC[r * 64 + (((g    ) ^ (r & 7)) << 3)];
            af[fi][1] = *(const bf16x8*)&AsC[r * 64 + (((4 + g) ^ (r & 7)) << 3)];
        }
#pragma unroll
        for (int fj = 0; fj < 2; fj++) {
            int r = wc * 32 + fj * 16 + c16;
            bfr[fj][0] = *(const bf16x8*)&BsC[r * 64 + (((g    ) ^ (r & 7)) << 3)];
            bfr[fj][1] = *(const bf16x8*)&BsC[r * 64 + (((4 + g) ^ (r & 7)) << 3)];
        }
#pragma unroll
        for (int fi = 0; fi < 4; fi++)
#pragma unroll
            for (int fj = 0; fj < 2; fj++) {
                acc[fi][fj] = MFMA16(af[fi][0], bfr[fj][0], acc[fi][fj]);
                acc[fi][fj] = MFMA16(af[fi][1], bfr[fj][1], acc[fi][fj]);
            }
        __syncthreads();
        cur ^= 1;
    }
#undef STAGE_N64

#pragma unroll
    for (int fi = 0; fi < 4; fi++)
#pragma unroll
        for (int fj = 0; fj < 2; fj++) {
            int coln = n0 + wc * 32 + fj * 16 + c16;
            float bv = BIAS ? bias[coln] : 0.f;
#pragma unroll
            for (int reg = 0; reg < 4; reg++) {
                int rowm = m0 + wr * 64 + fi * 16 + 4 * g + reg;
                float v = acc[fi][fj][reg] + bv;
                if (RES) v += res[(size_t)rowm * N + coln];
                if (RELU) v = fmaxf(v, 0.f);
                if (OBF) ((u16*)Cout)[(size_t)rowm * N + coln] = f2b(v);
                else     ((float*)Cout)[(size_t)rowm * N + coln] = v;
            }
        }
}

// ---------------------------------------------------------------------------
// qkv bf16 [4096][3072] (v at col 2048+h*64+d) -> vT bf16 [(b*16+h)*64+d][2048]
// ---------------------------------------------------------------------------
__global__ __launch_bounds__(256) void v_transpose(
    const u16* __restrict__ qkv, u16* __restrict__ vT)
{
    int t0 = blockIdx.x * 64, h = blockIdx.y, b = blockIdx.z;
    __shared__ u16 t[64][72];
    int tid = threadIdx.x;
#pragma unroll
    for (int it = 0; it < 2; it++) {
        int r = it * 32 + (tid >> 3);
        int cs = (tid & 7) * 8;
        *(uint4*)&t[r][cs] =
            *(const uint4*)(qkv + (size_t)(b * 2048 + t0 + r) * 3072 + 2048 + h * 64 + cs);
    }
    __syncthreads();
    int d = tid >> 2, seg = tid & 3;
    union { u16 u[8]; uint4 q; } pk;
#pragma unroll
    for (int hq = 0; hq < 2; hq++) {
#pragma unroll
        for (int j = 0; j < 8; j++) pk.u[j] = t[seg * 16 + hq * 8 + j][d];
        *(uint4*)(vT + (size_t)((b * 16 + h) * 64 + d) * 2048 + t0 + seg * 16 + hq * 8) = pk.q;
    }
}

// ---------------------------------------------------------------------------
// MFMA flash attention (causal, no 1/sqrt(d) scale — per reference).
// QBLK=128, 8 waves = (kg k-half) x (qg 32 q-rows); swapped QK^T; no-max
// softmax; counted-vmcnt double-buffered K/V; balanced qt mapping.
// ---------------------------------------------------------------------------
__global__ __launch_bounds__(512) void attn_mfma(
    const u16* __restrict__ qkv, const u16* __restrict__ vT,
    u16* __restrict__ outb)
{
    __shared__ u16 smem[24576];    // Ks 2x8KB | Vs 2x8KB | Ps 16KB = 48KB
    u16* KsB = smem;               // [2][4096]
    u16* VsB = smem + 8192;        // [2][4096]
    u16* PsB = smem + 16384;       // 128 q-rows x 64 k, stride 64 + XOR swz
    const int tid = threadIdx.x, l = tid & 63, w = tid >> 6;   // w 0..7
    const int g = l >> 4, c16 = l & 15;
    const int qg = w & 3, kg = w >> 2;            // q-group, k-half
    const int kg32 = kg * 32, kg64 = kg * 64;
    const int bh = blockIdx.y, b = bh >> 4, h = bh & 15;
    const int bx = (int)blockIdx.x;
    const int qt = (bh < 16) ? (15 - bx) : bx;    // balanced pair mapping
    const int r0 = qt * 128;
    const int wq0 = r0 + qg * 32;                 // wave's base q-row (32 rows)

    bf16x8 qf[2][2];
#pragma unroll
    for (int grp = 0; grp < 2; grp++) {
        const u16* qrow = qkv + (size_t)(b * 2048 + wq0 + grp * 16 + c16) * 3072 + h * 64;
        qf[grp][0] = *(const bf16x8*)(qrow + g * 8);
        qf[grp][1] = *(const bf16x8*)(qrow + 32 + g * 8);
    }

    const int kr = tid >> 3, ks = (tid & 7) ^ (kr & 7);
    const u16* kgp = qkv + (size_t)(b * 2048) * 3072 + 1024 + h * 64;
    const u16* vgp = vT + (size_t)((b * 16 + h) * 64) * 2048;

    float lrow[2] = {0.f, 0.f};
    f32x4 oacc[2][4];
#pragma unroll
    for (int grp = 0; grp < 2; grp++)
#pragma unroll
        for (int i = 0; i < 4; i++) oacc[grp][i] = (f32x4){0.f, 0.f, 0.f, 0.f};

    const int prow0 = (qg * 32 + c16) * 128;      // BYTE row base (grp0)
    const int swz   = (c16 & 7) << 4;             // 16B-chunk XOR (bytes)

#define STAGE_KV(nb, s0) do {                                                  \
        GLL16(kgp + (size_t)((s0) + kr) * 3072 + ks * 8, &KsB[(nb)*4096 + tid*8]); \
        GLL16(vgp + (size_t)kr * 2048 + (s0) + ks * 8, &VsB[(nb)*4096 + tid*8]);   \
    } while (0)

    STAGE_KV(0, 0);
    asm volatile("s_waitcnt vmcnt(0)" ::: "memory");
    __builtin_amdgcn_sched_barrier(0);
    __builtin_amdgcn_s_barrier();                 // buf0 certified for all

    const int nt = 2 * qt + 2;                    // 64-col K-tiles
    int cur = 0;
    for (int kt = 0; kt < nt; kt++) {
        if (kt + 1 < nt) STAGE_KV(cur ^ 1, (kt + 1) * 64);
        if (kt > 0) {
            if (kt + 1 < nt) asm volatile("s_waitcnt vmcnt(2)" ::: "memory");
            else             asm volatile("s_waitcnt vmcnt(0)" ::: "memory");
            __builtin_amdgcn_sched_barrier(0);
            __builtin_amdgcn_s_barrier();
        }
        const u16* KsC = &KsB[cur * 4096];
        const u16* VsC = &VsB[cur * 4096];
        const int s0 = kt * 64;

        bf16x8 kf0[2], kf1[2];
#pragma unroll
        for (int fj = 0; fj < 2; fj++) {
            int r = kg32 + fj * 16 + c16;
            kf0[fj] = *(const bf16x8*)&KsC[r * 64 + ((g       ^ (r & 7)) << 3)];
            kf1[fj] = *(const bf16x8*)&KsC[r * 64 + (((4 + g) ^ (r & 7)) << 3)];
        }
#pragma unroll
        for (int grp = 0; grp < 2; grp++) {
            f32x4 sc[2];
            sc[0] = (f32x4){0.f, 0.f, 0.f, 0.f};
            sc[1] = (f32x4){0.f, 0.f, 0.f, 0.f};
#pragma unroll
            for (int fj = 0; fj < 2; fj++) {
                sc[fj] = MFMA16(kf0[fj], qf[grp][0], sc[fj]);   // SWAPPED: S^T
                sc[fj] = MFMA16(kf1[fj], qf[grp][1], sc[fj]);
            }
            const int qgl = wq0 + grp * 16 + c16;  // this lane's q row
            if (s0 + kg32 + 31 > wq0 + grp * 16) { // causal frontier possible
#pragma unroll
                for (int fj = 0; fj < 2; fj++)
#pragma unroll
                    for (int reg = 0; reg < 4; reg++)
                        if (s0 + kg32 + fj * 16 + 4 * g + reg > qgl)
                            sc[fj][reg] = -1e30f;
            }
#pragma unroll
            for (int fj = 0; fj < 2; fj++) {
                float p0 = __expf(sc[fj][0]);
                float p1 = __expf(sc[fj][1]);
                float p2 = __expf(sc[fj][2]);
                float p3 = __expf(sc[fj][3]);
                lrow[grp] += (p0 + p1) + (p2 + p3);
                uint2 pk;
                pk.x = cvtpk(p0, p1);
                pk.y = cvtpk(p2, p3);
                *(uint2*)((char*)PsB + prow0 + grp * 2048 +
                          ((kg64 + fj * 32 + 8 * g) ^ swz)) = pk;
            }
        }
        bf16x8 pa0 = *(const bf16x8*)((const char*)PsB + prow0 +
                                      ((kg64 + 16 * g) ^ swz));
        bf16x8 pa1 = *(const bf16x8*)((const char*)PsB + prow0 + 2048 +
                                      ((kg64 + 16 * g) ^ swz));
#pragma unroll
        for (int fd = 0; fd < 4; fd++) {
            int r = fd * 16 + c16;
            bf16x8 vf = *(const bf16x8*)&VsC[r * 64 + (((4 * kg + g) ^ (r & 7)) << 3)];
            oacc[0][fd] = MFMA16(pa0, vf, oacc[0][fd]);
            oacc[1][fd] = MFMA16(pa1, vf, oacc[1][fd]);
        }
        __builtin_amdgcn_s_barrier();
        cur ^= 1;
    }
#undef STAGE_KV

#pragma unroll
    for (int grp = 0; grp < 2; grp++) {
        lrow[grp] += __shfl_xor(lrow[grp], 16);
        lrow[grp] += __shfl_xor(lrow[grp], 32);
    }

    __syncthreads();
    float* scr = (float*)smem;                     // 48KB >= 4*64*36*4B
    const int sbase = qg * 2304 + l * 36;          // 16B-aligned per lane
    if (kg == 1) {
#pragma unroll
        for (int grp = 0; grp < 2; grp++) {
#pragma unroll
            for (int fd = 0; fd < 4; fd++)
                *(f32x4*)&scr[sbase + grp * 16 + fd * 4] = oacc[grp][fd];
            scr[sbase + 32 + grp] = lrow[grp];
        }
    }
    __syncthreads();
    if (kg == 0) {
#pragma unroll
        for (int grp = 0; grp < 2; grp++) {
#pragma unroll
            for (int fd = 0; fd < 4; fd++)
                oacc[grp][fd] += *(const f32x4*)&scr[sbase + grp * 16 + fd * 4];
            float lr = lrow[grp] + scr[sbase + 32 + grp];
#pragma unroll
            for (int reg = 0; reg < 4; reg++) {
                float ls = __shfl(lr, 4 * g + reg);   // lsum of q-row 4g+reg
                float inv = 1.0f / ls;
                int t = wq0 + grp * 16 + 4 * g + reg;
                u16* op = outb + (size_t)(b * 2048 + t) * 1024 + h * 64;
#pragma unroll
                for (int fd = 0; fd < 4; fd++)
                    op[fd * 16 + c16] = f2b(oacc[grp][fd][reg] * inv);
            }
        }
    }
}

// ---------------------------------------------------------------------------
extern "C" void kernel_launch(void* const* d_in, const int* in_sizes, int n_in,
                              void* d_out, int out_size, void* d_ws, size_t ws_size,
                              hipStream_t stream) {
    const float* x     = (const float*)d_in[0];
    const float* ln1w  = (const float*)d_in[1];
    const float* ln1b  = (const float*)d_in[2];
    const float* Wq    = (const float*)d_in[3];
    const float* Wk    = (const float*)d_in[4];
    const float* Wv    = (const float*)d_in[5];
    const float* projw = (const float*)d_in[6];
    const float* projb = (const float*)d_in[7];
    const float* ln2w  = (const float*)d_in[8];
    const float* ln2b  = (const float*)d_in[9];
    const float* fc1w  = (const float*)d_in[10];
    const float* fc1b  = (const float*)d_in[11];
    const float* fc2w  = (const float*)d_in[12];
    const float* fc2b  = (const float*)d_in[13];
    float* out = (float*)d_out;

    u16* h_bf    = (u16*)d_ws;                 // 4096*1024
    u16* qkv_bf  = h_bf    + 4194304;          // 4096*3072
    u16* vTb     = qkv_bf  + 12582912;         // 2048*2048
    u16* attn_bf = vTb     + 4194304;          // 4096*1024
    u16* ff1_bf  = attn_bf + 4194304;          // 4096*4096
    u16* WtQKV   = ff1_bf  + 16777216;         // 3072*1024
    u16* WtP     = WtQKV   + 3145728;          // 1024*1024
    u16* Wt1     = WtP     + 1048576;          // 4096*1024
    u16* Wt2     = Wt1     + 4194304;          // 1024*4096
    u16* x1_bf   = Wt2     + 4194304;          // 4096*1024 (x + sa, bf16)
    // FC2 split-K bf16 partials (4 x 4096x1024 u16 = 32MB) reuse the
    // h_bf..qkv_bf region (dead by FC2 time; rewritten every launch).
    u16* fc2p = (u16*)d_ws;

    // fused prologue: 4 weight repacks + LN1 in one launch
    repack_all<<<dim3(4096), 256, 0, stream>>>(
        Wq, Wk, Wv, WtQKV, projw, WtP, fc1w, Wt1, fc2w, Wt2,
        x, ln1w, ln1b, h_bf);

    gemm_qkv<<<dim3(256), 512, 0, stream>>>(h_bf, WtQKV, qkv_bf);
    v_transpose<<<dim3(32, 16, 2), 256, 0, stream>>>(qkv_bf, vTb);
    attn_mfma<<<dim3(16, 32), 512, 0, stream>>>(qkv_bf, vTb, attn_bf);
    gemm_n64<1, 1, 1, 0><<<dim3(16, 32), 256, 0, stream>>>(
        attn_bf, WtP, projb, x, x1_bf, Mn, 1024, 1024);
    ln_bf16_b<<<1024, 256, 0, stream>>>(x1_bf, ln2w, ln2b, h_bf);
    gemm_8ph<1, 1, 1><<<dim3(256), 512, 0, stream>>>(
        h_bf, Wt1, fc1b, ff1_bf, Mn, 4096, 1024, 16);
    gemm_fc2<<<dim3(256), 512, 0, stream>>>(ff1_bf, Wt2, fc2p);
    splitk_reduce<<<dim3(4096), 256, 0, stream>>>(fc2p, x1_bf, fc2b, out);
}